// Round 14
// baseline (307.702 us; speedup 1.0000x reference)
//
#include <hip/hip_runtime.h>
#include <hip/hip_bf16.h>
#include <math.h>

// ---------------------------------------------------------------------------
// GCN anomaly detector.
// Round 13 landed tail fusion (333->298us). Round 14: delete the DEAD
// src-sort from k_bucketbuild -- rounds 10-12 proved sorted CSR lists give
// zero agg benefit, but the sort still cost 132KB LDS (1 block/CU!) and 3
// extra LDS passes. Lean version: 5KB LDS (h+sm), full occupancy, pairs
// read twice from global (2nd read L2-warm, ~65KB/bucket).
// Pipeline: CSR build (atomic-free counting sort) -> GEMM1 -> gather-agg
// (bf16 packed, register acc, unroll 8) -> GEMM2 -> agg32 -> fused tail
// (recon MLP + scorer MLP + score, weights+intermediates in LDS).
// ---------------------------------------------------------------------------

__global__ void k_detect(const unsigned int* __restrict__ w, int npairs,
                         int* __restrict__ meta) {
  __shared__ int any;
  if (threadIdx.x == 0) any = 0;
  __syncthreads();
  int local = 0;
  for (int i = threadIdx.x; i < npairs; i += blockDim.x)
    local |= (w[2 * i + 1] != 0u);
  if (local) atomicOr(&any, 1);
  __syncthreads();
  if (threadIdx.x == 0) meta[0] = any ? 0 : 1;  // 1 => edge_index is int64
}

// P1: per-chunk LDS histogram over dst buckets. hist layout: [bin][chunk].
__global__ __launch_bounds__(256) void k_binhist(const void* __restrict__ ei,
                                                 int E, int CS, int B, int shift,
                                                 const int* __restrict__ meta,
                                                 int* __restrict__ hist, int C) {
  __shared__ int lh[256];
  int c = blockIdx.x;
  for (int i = threadIdx.x; i < B; i += 256) lh[i] = 0;
  __syncthreads();
  int e0 = c * CS, e1 = min(E, e0 + CS);
  bool is64 = meta[0] != 0;
  for (int e = e0 + threadIdx.x; e < e1; e += 256) {
    int d = is64 ? (int)((const long long*)ei)[(long)E + e]
                 : ((const int*)ei)[(long)E + e];
    atomicAdd(&lh[d >> shift], 1);
  }
  __syncthreads();
  for (int b = threadIdx.x; b < B; b += 256) hist[(long)b * C + c] = lh[b];
}

// P3: re-read edges, write packed (dstInBucket<<SB | src) into reserved
// per-(chunk,bin) ranges. LDS cursors only -> zero global atomics.
__global__ __launch_bounds__(256) void k_binscatter(const void* __restrict__ ei,
                                                    int E, int CS, int B, int shift,
                                                    int SB,
                                                    const int* __restrict__ meta,
                                                    const int* __restrict__ scan,
                                                    int C, unsigned* __restrict__ pairs) {
  __shared__ int cur[256];
  int c = blockIdx.x;
  for (int b = threadIdx.x; b < B; b += 256) cur[b] = scan[(long)b * C + c];
  __syncthreads();
  int e0 = c * CS, e1 = min(E, e0 + CS);
  bool is64 = meta[0] != 0;
  unsigned spb1 = (1u << shift) - 1u;
  for (int e = e0 + threadIdx.x; e < e1; e += 256) {
    int s, d;
    if (is64) {
      const long long* p = (const long long*)ei;
      s = (int)p[e]; d = (int)p[(long)E + e];
    } else {
      const int* p = (const int*)ei;
      s = p[e]; d = p[(long)E + e];
    }
    int pos = atomicAdd(&cur[d >> shift], 1);
    pairs[pos] = (((unsigned)d & spb1) << SB) | (unsigned)s;
  }
}

// P4 (fused, LEAN): per-bucket degree hist -> cnt, dis, rs; LDS exclusive
// scan; cursors stay in LDS; scatter src into final CSR. 5KB LDS only --
// pairs read twice from global (2nd read L2-warm).
__global__ __launch_bounds__(256) void k_bucketbuild(const unsigned* __restrict__ pairs,
                                                     const int* __restrict__ scan,
                                                     int C, int shift, int SB, int N,
                                                     int* __restrict__ cnt,
                                                     float* __restrict__ dis,
                                                     int* __restrict__ rs,
                                                     int* __restrict__ csr) {
  __shared__ int h[1024];
  __shared__ int sm[256];
  int bin = blockIdx.x;
  int base = bin << shift;
  int nn = min(N - base, 1 << shift);
  int t = threadIdx.x;
  unsigned smask = (1u << SB) - 1u;
  for (int i = t; i < 1024; i += 256) h[i] = 0;
  __syncthreads();
  int p0 = scan[(long)bin * C];
  int p1 = scan[(long)(bin + 1) * C];  // sentinel row gives E for last bucket
  for (int i = p0 + t; i < p1; i += 256)
    atomicAdd(&h[pairs[i] >> SB], 1);
  __syncthreads();
  int v0 = h[4 * t], v1 = h[4 * t + 1], v2 = h[4 * t + 2], v3 = h[4 * t + 3];
  int s = v0 + v1 + v2 + v3;
  sm[t] = s;
  __syncthreads();
  for (int off = 1; off < 256; off <<= 1) {
    int x = (t >= off) ? sm[t - off] : 0;
    __syncthreads();
    sm[t] += x;
    __syncthreads();
  }
  int run = p0 + sm[t] - s;
  int r0 = run, r1 = run + v0, r2 = r1 + v1, r3 = r2 + v2;
  h[4 * t] = r0; h[4 * t + 1] = r1; h[4 * t + 2] = r2; h[4 * t + 3] = r3;
  if (4 * t + 0 < nn) { cnt[base + 4*t+0] = v0; dis[base + 4*t+0] = rsqrtf((float)v0 + 1.f); rs[base + 4*t+0] = r0; }
  if (4 * t + 1 < nn) { cnt[base + 4*t+1] = v1; dis[base + 4*t+1] = rsqrtf((float)v1 + 1.f); rs[base + 4*t+1] = r1; }
  if (4 * t + 2 < nn) { cnt[base + 4*t+2] = v2; dis[base + 4*t+2] = rsqrtf((float)v2 + 1.f); rs[base + 4*t+2] = r2; }
  if (4 * t + 3 < nn) { cnt[base + 4*t+3] = v3; dis[base + 4*t+3] = rsqrtf((float)v3 + 1.f); rs[base + 4*t+3] = r3; }
  __syncthreads();
  for (int i = p0 + t; i < p1; i += 256) {
    unsigned p = pairs[i];
    int pos = atomicAdd(&h[p >> SB], 1);
    csr[pos] = (int)(p & smask);
  }
}

__global__ __launch_bounds__(1024) void k_scan1(const int* __restrict__ cnt,
                                                int* __restrict__ bsums, int n) {
  __shared__ int sm[1024];
  int t = threadIdx.x;
  long i = (long)blockIdx.x * 1024 + t;
  sm[t] = (i < n) ? cnt[i] : 0;
  __syncthreads();
  for (int s = 512; s > 0; s >>= 1) {
    if (t < s) sm[t] += sm[t + s];
    __syncthreads();
  }
  if (t == 0) bsums[blockIdx.x] = sm[0];
}

__global__ void k_scan2(int* __restrict__ bsums, int nb) {
  __shared__ int sm[128];
  int t = threadIdx.x;
  int v = (t < nb) ? bsums[t] : 0;
  sm[t] = v;
  __syncthreads();
  for (int off = 1; off < 128; off <<= 1) {
    int x = (t >= off) ? sm[t - off] : 0;
    __syncthreads();
    sm[t] += x;
    __syncthreads();
  }
  if (t < nb) bsums[t] = sm[t] - v;  // exclusive
}

// exclusive scan -> out (may alias in); optional sentinel out[n] = total.
__global__ __launch_bounds__(1024) void k_scan3s(const int* __restrict__ in,
                                                 const int* __restrict__ bsums,
                                                 int* __restrict__ out, int n,
                                                 int sentinel) {
  __shared__ int sm[1024];
  int t = threadIdx.x;
  long i = (long)blockIdx.x * 1024 + t;
  int v = (i < n) ? in[i] : 0;
  sm[t] = v;
  __syncthreads();
  for (int off = 1; off < 1024; off <<= 1) {
    int x = (t >= off) ? sm[t - off] : 0;
    __syncthreads();
    sm[t] += x;
    __syncthreads();
  }
  int excl = sm[t] - v + bsums[blockIdx.x];
  if (i < n) out[i] = excl;
  if (sentinel && i == n - 1) out[n] = excl + v;
}

__device__ __forceinline__ float bfu(unsigned short u) {
  return __uint_as_float((unsigned)u << 16);
}
__device__ __forceinline__ float bf_lo(unsigned u) {
  return __uint_as_float(u << 16);
}
__device__ __forceinline__ float bf_hi(unsigned u) {
  return __uint_as_float(u & 0xffff0000u);
}
__device__ __forceinline__ unsigned pack_bf2(float lo, float hi) {
  __hip_bfloat16 a = __float2bfloat16(lo), b = __float2bfloat16(hi);
  return (unsigned)*(unsigned short*)&a | ((unsigned)*(unsigned short*)&b << 16);
}

// C[n, M] = act(A[n, K] @ W[K, M] (+ bias)); W row-major [K][M], staged in LDS.
// K-loop pinned to no-unroll + manual next-k prefetch.
// ABF16: A rows are bf16. OBF16: write output as bf16 (RNE).
template <int K, int M, bool BIAS, int ACT, bool ABF16, bool OBF16>
__global__ __launch_bounds__(256) void k_gemm(const void* __restrict__ Av,
                                              const float* __restrict__ W,
                                              const float* __restrict__ bias,
                                              void* __restrict__ Cout, int nrows) {
  constexpr int CP = 4;
  constexpr int TPR = M / CP;        // threads per row
  constexpr int RG = 256 / TPR;      // row-groups per block
  constexpr int RP = 4;              // rows per thread
  constexpr int RT = RG * RP;        // rows per block
  __shared__ __align__(16) float sW[K * M];
  __shared__ __align__(16) float sB[BIAS ? M : 4];

  for (int i = threadIdx.x; i < K * M / 4; i += 256)
    ((float4*)sW)[i] = ((const float4*)W)[i];
  if (BIAS)
    for (int i = threadIdx.x; i < M; i += 256) sB[i] = bias[i];
  __syncthreads();

  const int cg = threadIdx.x % TPR;
  const int rg = threadIdx.x / TPR;
  const long row0 = (long)blockIdx.x * RT + rg;

  const float4* Apf[RP];
  const ushort4* Apb[RP];
  bool valid[RP];
#pragma unroll
  for (int r = 0; r < RP; ++r) {
    long row = row0 + (long)r * RG;
    valid[r] = (row < nrows);
    long rr = valid[r] ? row : 0;
    if (ABF16) Apb[r] = (const ushort4*)((const unsigned short*)Av + rr * K);
    else       Apf[r] = (const float4*)((const float*)Av + rr * K);
  }

  auto loadA = [&](int r, int k4) -> float4 {
    if (!valid[r]) return make_float4(0.f, 0.f, 0.f, 0.f);
    if (ABF16) {
      ushort4 q = Apb[r][k4];
      return make_float4(bfu(q.x), bfu(q.y), bfu(q.z), bfu(q.w));
    }
    return Apf[r][k4];
  };

  float acc[RP][CP] = {};
  float4 a[RP];
#pragma unroll
  for (int r = 0; r < RP; ++r) a[r] = loadA(r, 0);

#pragma unroll 1
  for (int k0 = 0; k0 < K - 4; k0 += 4) {
    float4 an[RP];
#pragma unroll
    for (int r = 0; r < RP; ++r) an[r] = loadA(r, k0 / 4 + 1);
#pragma unroll
    for (int j = 0; j < 4; ++j) {
      float4 w = ((const float4*)(sW + (k0 + j) * M))[cg];
#pragma unroll
      for (int r = 0; r < RP; ++r) {
        float av = (j == 0) ? a[r].x : (j == 1) ? a[r].y : (j == 2) ? a[r].z : a[r].w;
        acc[r][0] += av * w.x;
        acc[r][1] += av * w.y;
        acc[r][2] += av * w.z;
        acc[r][3] += av * w.w;
      }
    }
#pragma unroll
    for (int r = 0; r < RP; ++r) a[r] = an[r];
  }
  {  // last k-step
    const int k0 = K - 4;
#pragma unroll
    for (int j = 0; j < 4; ++j) {
      float4 w = ((const float4*)(sW + (k0 + j) * M))[cg];
#pragma unroll
      for (int r = 0; r < RP; ++r) {
        float av = (j == 0) ? a[r].x : (j == 1) ? a[r].y : (j == 2) ? a[r].z : a[r].w;
        acc[r][0] += av * w.x;
        acc[r][1] += av * w.y;
        acc[r][2] += av * w.z;
        acc[r][3] += av * w.w;
      }
    }
  }

#pragma unroll
  for (int r = 0; r < RP; ++r) {
    long row = row0 + (long)r * RG;
    if (row >= nrows) continue;
    float4 o = make_float4(acc[r][0], acc[r][1], acc[r][2], acc[r][3]);
    if (BIAS) {
      float4 bb = ((const float4*)sB)[cg];
      o.x += bb.x; o.y += bb.y; o.z += bb.z; o.w += bb.w;
    }
    if (ACT == 1) {
      o.x = fmaxf(o.x, 0.f); o.y = fmaxf(o.y, 0.f);
      o.z = fmaxf(o.z, 0.f); o.w = fmaxf(o.w, 0.f);
    }
    if (OBF16) {
      uint2 pk;
      pk.x = pack_bf2(o.x, o.y);
      pk.y = pack_bf2(o.z, o.w);
      ((uint2*)((__hip_bfloat16*)Cout + row * M))[cg] = pk;
    } else {
      ((float4*)((float*)Cout + row * M))[cg] = o;
    }
  }
}

// Pull aggregation, D=64 bf16: 16 lanes/node (4 feats = uint2 per lane),
// 4 nodes/wave, unroll 8. Output packed bf16 (uint2/lane).
__global__ __launch_bounds__(256) void k_agg64p(const uint2* __restrict__ hw,
                                                const int* __restrict__ csr,
                                                const int* __restrict__ rs,
                                                const int* __restrict__ cnt,
                                                const float* __restrict__ dis,
                                                const float* __restrict__ b,
                                                uint2* __restrict__ out, int n) {
  unsigned node = blockIdx.x * 16u + (threadIdx.x >> 4);
  if (node >= (unsigned)n) return;
  unsigned f4 = threadIdx.x & 15;
  float dsn = dis[node];
  uint2 su = hw[node * 16u + f4];
  float d2 = dsn * dsn;
  float a0 = bf_lo(su.x) * d2, a1 = bf_hi(su.x) * d2;
  float a2 = bf_lo(su.y) * d2, a3 = bf_hi(su.y) * d2;
  int start = rs[node], deg = cnt[node];
  int e = 0;
  for (; e + 7 < deg; e += 8) {
    unsigned s0 = (unsigned)csr[start + e];
    unsigned s1 = (unsigned)csr[start + e + 1];
    unsigned s2 = (unsigned)csr[start + e + 2];
    unsigned s3 = (unsigned)csr[start + e + 3];
    unsigned s4 = (unsigned)csr[start + e + 4];
    unsigned s5 = (unsigned)csr[start + e + 5];
    unsigned s6 = (unsigned)csr[start + e + 6];
    unsigned s7 = (unsigned)csr[start + e + 7];
    float w0 = dis[s0] * dsn, w1 = dis[s1] * dsn;
    float w2 = dis[s2] * dsn, w3 = dis[s3] * dsn;
    float w4 = dis[s4] * dsn, w5 = dis[s5] * dsn;
    float w6 = dis[s6] * dsn, w7 = dis[s7] * dsn;
    uint2 u0 = hw[s0 * 16u + f4];
    uint2 u1 = hw[s1 * 16u + f4];
    uint2 u2 = hw[s2 * 16u + f4];
    uint2 u3 = hw[s3 * 16u + f4];
    uint2 u4 = hw[s4 * 16u + f4];
    uint2 u5 = hw[s5 * 16u + f4];
    uint2 u6 = hw[s6 * 16u + f4];
    uint2 u7 = hw[s7 * 16u + f4];
    a0 += bf_lo(u0.x) * w0 + bf_lo(u1.x) * w1 + bf_lo(u2.x) * w2 + bf_lo(u3.x) * w3
        + bf_lo(u4.x) * w4 + bf_lo(u5.x) * w5 + bf_lo(u6.x) * w6 + bf_lo(u7.x) * w7;
    a1 += bf_hi(u0.x) * w0 + bf_hi(u1.x) * w1 + bf_hi(u2.x) * w2 + bf_hi(u3.x) * w3
        + bf_hi(u4.x) * w4 + bf_hi(u5.x) * w5 + bf_hi(u6.x) * w6 + bf_hi(u7.x) * w7;
    a2 += bf_lo(u0.y) * w0 + bf_lo(u1.y) * w1 + bf_lo(u2.y) * w2 + bf_lo(u3.y) * w3
        + bf_lo(u4.y) * w4 + bf_lo(u5.y) * w5 + bf_lo(u6.y) * w6 + bf_lo(u7.y) * w7;
    a3 += bf_hi(u0.y) * w0 + bf_hi(u1.y) * w1 + bf_hi(u2.y) * w2 + bf_hi(u3.y) * w3
        + bf_hi(u4.y) * w4 + bf_hi(u5.y) * w5 + bf_hi(u6.y) * w6 + bf_hi(u7.y) * w7;
  }
  for (; e < deg; ++e) {
    unsigned s0 = (unsigned)csr[start + e];
    float w0 = dis[s0] * dsn;
    uint2 u0 = hw[s0 * 16u + f4];
    a0 += bf_lo(u0.x) * w0;
    a1 += bf_hi(u0.x) * w0;
    a2 += bf_lo(u0.y) * w0;
    a3 += bf_hi(u0.y) * w0;
  }
  float4 bb = ((const float4*)b)[f4];
  uint2 pk;
  pk.x = pack_bf2(fmaxf(a0 + bb.x, 0.f), fmaxf(a1 + bb.y, 0.f));  // relu
  pk.y = pack_bf2(fmaxf(a2 + bb.z, 0.f), fmaxf(a3 + bb.w, 0.f));
  out[node * 16u + f4] = pk;
}

// Pull aggregation, D=32 bf16: 8 lanes/node (4 feats = uint2 per lane),
// 8 nodes/wave, unroll 8. fp32 output (this IS the h output in d_out).
__global__ __launch_bounds__(256) void k_agg32p(const uint2* __restrict__ hw,
                                                const int* __restrict__ csr,
                                                const int* __restrict__ rs,
                                                const int* __restrict__ cnt,
                                                const float* __restrict__ dis,
                                                const float* __restrict__ b,
                                                float* __restrict__ out, int n) {
  unsigned node = blockIdx.x * 32u + (threadIdx.x >> 3);
  if (node >= (unsigned)n) return;
  unsigned f4 = threadIdx.x & 7;
  float dsn = dis[node];
  uint2 su = hw[node * 8u + f4];
  float d2 = dsn * dsn;
  float a0 = bf_lo(su.x) * d2, a1 = bf_hi(su.x) * d2;
  float a2 = bf_lo(su.y) * d2, a3 = bf_hi(su.y) * d2;
  int start = rs[node], deg = cnt[node];
  int e = 0;
  for (; e + 7 < deg; e += 8) {
    unsigned s0 = (unsigned)csr[start + e];
    unsigned s1 = (unsigned)csr[start + e + 1];
    unsigned s2 = (unsigned)csr[start + e + 2];
    unsigned s3 = (unsigned)csr[start + e + 3];
    unsigned s4 = (unsigned)csr[start + e + 4];
    unsigned s5 = (unsigned)csr[start + e + 5];
    unsigned s6 = (unsigned)csr[start + e + 6];
    unsigned s7 = (unsigned)csr[start + e + 7];
    float w0 = dis[s0] * dsn, w1 = dis[s1] * dsn;
    float w2 = dis[s2] * dsn, w3 = dis[s3] * dsn;
    float w4 = dis[s4] * dsn, w5 = dis[s5] * dsn;
    float w6 = dis[s6] * dsn, w7 = dis[s7] * dsn;
    uint2 u0 = hw[s0 * 8u + f4];
    uint2 u1 = hw[s1 * 8u + f4];
    uint2 u2 = hw[s2 * 8u + f4];
    uint2 u3 = hw[s3 * 8u + f4];
    uint2 u4 = hw[s4 * 8u + f4];
    uint2 u5 = hw[s5 * 8u + f4];
    uint2 u6 = hw[s6 * 8u + f4];
    uint2 u7 = hw[s7 * 8u + f4];
    a0 += bf_lo(u0.x) * w0 + bf_lo(u1.x) * w1 + bf_lo(u2.x) * w2 + bf_lo(u3.x) * w3
        + bf_lo(u4.x) * w4 + bf_lo(u5.x) * w5 + bf_lo(u6.x) * w6 + bf_lo(u7.x) * w7;
    a1 += bf_hi(u0.x) * w0 + bf_hi(u1.x) * w1 + bf_hi(u2.x) * w2 + bf_hi(u3.x) * w3
        + bf_hi(u4.x) * w4 + bf_hi(u5.x) * w5 + bf_hi(u6.x) * w6 + bf_hi(u7.x) * w7;
    a2 += bf_lo(u0.y) * w0 + bf_lo(u1.y) * w1 + bf_lo(u2.y) * w2 + bf_lo(u3.y) * w3
        + bf_lo(u4.y) * w4 + bf_lo(u5.y) * w5 + bf_lo(u6.y) * w6 + bf_lo(u7.y) * w7;
    a3 += bf_hi(u0.y) * w0 + bf_hi(u1.y) * w1 + bf_hi(u2.y) * w2 + bf_hi(u3.y) * w3
        + bf_hi(u4.y) * w4 + bf_hi(u5.y) * w5 + bf_hi(u6.y) * w6 + bf_hi(u7.y) * w7;
  }
  for (; e < deg; ++e) {
    unsigned s0 = (unsigned)csr[start + e];
    float w0 = dis[s0] * dsn;
    uint2 u0 = hw[s0 * 8u + f4];
    a0 += bf_lo(u0.x) * w0;
    a1 += bf_hi(u0.x) * w0;
    a2 += bf_lo(u0.y) * w0;
    a3 += bf_hi(u0.y) * w0;
  }
  float4 bb = ((const float4*)b)[f4];
  ((float4*)(out + node * 32u))[f4] =
      make_float4(a0 + bb.x, a1 + bb.y, a2 + bb.z, a3 + bb.w);
}

// Fused tail: per block of 64 nodes, from h (fp32 [N,32] in d_out):
//   t = relu(h@rW1+rb1)   [64][64] LDS (fp32, never global)
//   x_rec = t@rW2+rb2     -> global fp32 [N,128]
//   s = relu(h@sW1+sb1)   [64][32] LDS
//   score = sigmoid(s.sW2+sb2) -> global [N,1]
// Padded LDS strides (33/65) kill bank conflicts on row-indexed reads.
__global__ __launch_bounds__(256) void k_tail(const float* __restrict__ h,
                                              const float* __restrict__ rW1,
                                              const float* __restrict__ rb1,
                                              const float* __restrict__ rW2,
                                              const float* __restrict__ rb2,
                                              const float* __restrict__ sW1,
                                              const float* __restrict__ sb1,
                                              const float* __restrict__ sW2,
                                              const float* __restrict__ sb2,
                                              float* __restrict__ x_rec,
                                              float* __restrict__ score, int n) {
  __shared__ __align__(16) float sRW1[32 * 64];    // 8 KB
  __shared__ __align__(16) float sRW2[64 * 128];   // 32 KB
  __shared__ __align__(16) float sSW1[32 * 32];    // 4 KB
  __shared__ __align__(16) float sRB1[64];
  __shared__ __align__(16) float sRB2[128];
  __shared__ __align__(16) float sSB1[32];
  __shared__ __align__(16) float sSW2[32];
  __shared__ float sH[64 * 33];                    // 8.45 KB
  __shared__ float sT[64 * 65];                    // 16.6 KB
  __shared__ float sS[64 * 33];                    // 8.45 KB
  int t = threadIdx.x;
  for (int i = t; i < 32 * 64 / 4; i += 256) ((float4*)sRW1)[i] = ((const float4*)rW1)[i];
  for (int i = t; i < 64 * 128 / 4; i += 256) ((float4*)sRW2)[i] = ((const float4*)rW2)[i];
  for (int i = t; i < 32 * 32 / 4; i += 256) ((float4*)sSW1)[i] = ((const float4*)sW1)[i];
  if (t < 64) sRB1[t] = rb1[t];
  else if (t < 192) sRB2[t - 64] = rb2[t - 64];
  else if (t < 224) sSB1[t - 192] = sb1[t - 192];
  else sSW2[t - 224] = sW2[t - 224];

  long base = (long)blockIdx.x * 64;
  int nn = (int)min(64L, (long)n - base);
  if (nn < 0) nn = 0;
  for (int i = t; i < 64 * 8; i += 256) {          // 512 float4 loads of h
    int node = i >> 3, q = i & 7;
    float4 v = (node < nn) ? ((const float4*)(h + (base + node) * 32))[q]
                           : make_float4(0.f, 0.f, 0.f, 0.f);
    sH[node * 33 + 4 * q]     = v.x;
    sH[node * 33 + 4 * q + 1] = v.y;
    sH[node * 33 + 4 * q + 2] = v.z;
    sH[node * 33 + 4 * q + 3] = v.w;
  }
  __syncthreads();

  {  // phase T: M=64, TPR=16, RG=16, RP=4
    int cg = t & 15, rg = t >> 4;
    float acc[4][4] = {};
    for (int k = 0; k < 32; ++k) {
      float4 w = ((const float4*)(sRW1 + k * 64))[cg];
      float a0 = sH[rg * 33 + k];
      float a1 = sH[(rg + 16) * 33 + k];
      float a2 = sH[(rg + 32) * 33 + k];
      float a3 = sH[(rg + 48) * 33 + k];
      acc[0][0] += a0 * w.x; acc[0][1] += a0 * w.y; acc[0][2] += a0 * w.z; acc[0][3] += a0 * w.w;
      acc[1][0] += a1 * w.x; acc[1][1] += a1 * w.y; acc[1][2] += a1 * w.z; acc[1][3] += a1 * w.w;
      acc[2][0] += a2 * w.x; acc[2][1] += a2 * w.y; acc[2][2] += a2 * w.z; acc[2][3] += a2 * w.w;
      acc[3][0] += a3 * w.x; acc[3][1] += a3 * w.y; acc[3][2] += a3 * w.z; acc[3][3] += a3 * w.w;
    }
    float4 bb = ((const float4*)sRB1)[cg];
#pragma unroll
    for (int m = 0; m < 4; ++m) {
      int row = rg + 16 * m;
      sT[row * 65 + 4 * cg]     = fmaxf(acc[m][0] + bb.x, 0.f);
      sT[row * 65 + 4 * cg + 1] = fmaxf(acc[m][1] + bb.y, 0.f);
      sT[row * 65 + 4 * cg + 2] = fmaxf(acc[m][2] + bb.z, 0.f);
      sT[row * 65 + 4 * cg + 3] = fmaxf(acc[m][3] + bb.w, 0.f);
    }
  }
  {  // phase S: M=32, TPR=8, RG=32, RP=2 (reads sH only; disjoint write sS)
    int cg = t & 7, rg = t >> 3;
    float acc[2][4] = {};
    for (int k = 0; k < 32; ++k) {
      float4 w = ((const float4*)(sSW1 + k * 32))[cg];
      float a0 = sH[rg * 33 + k];
      float a1 = sH[(rg + 32) * 33 + k];
      acc[0][0] += a0 * w.x; acc[0][1] += a0 * w.y; acc[0][2] += a0 * w.z; acc[0][3] += a0 * w.w;
      acc[1][0] += a1 * w.x; acc[1][1] += a1 * w.y; acc[1][2] += a1 * w.z; acc[1][3] += a1 * w.w;
    }
    float4 bb = ((const float4*)sSB1)[cg];
#pragma unroll
    for (int m = 0; m < 2; ++m) {
      int row = rg + 32 * m;
      sS[row * 33 + 4 * cg]     = fmaxf(acc[m][0] + bb.x, 0.f);
      sS[row * 33 + 4 * cg + 1] = fmaxf(acc[m][1] + bb.y, 0.f);
      sS[row * 33 + 4 * cg + 2] = fmaxf(acc[m][2] + bb.z, 0.f);
      sS[row * 33 + 4 * cg + 3] = fmaxf(acc[m][3] + bb.w, 0.f);
    }
  }
  __syncthreads();

  {  // phase X: M=128, TPR=32, RG=8, RP=8 -> x_rec global
    int cg = t & 31, rg = t >> 5;
    float acc[8][4] = {};
    for (int k = 0; k < 64; ++k) {
      float4 w = ((const float4*)(sRW2 + k * 128))[cg];
#pragma unroll
      for (int m = 0; m < 8; ++m) {
        float a = sT[(rg + 8 * m) * 65 + k];
        acc[m][0] += a * w.x; acc[m][1] += a * w.y;
        acc[m][2] += a * w.z; acc[m][3] += a * w.w;
      }
    }
    float4 bb = ((const float4*)sRB2)[cg];
#pragma unroll
    for (int m = 0; m < 8; ++m) {
      int row = rg + 8 * m;
      if (row < nn) {
        float4 o = make_float4(acc[m][0] + bb.x, acc[m][1] + bb.y,
                               acc[m][2] + bb.z, acc[m][3] + bb.w);
        ((float4*)(x_rec + (base + row) * 128))[cg] = o;
      }
    }
  }
  if (t < nn) {  // score: one thread per node
    float acc = 0.f;
    for (int j = 0; j < 32; ++j) acc += sS[t * 33 + j] * sSW2[j];
    score[base + t] = 1.0f / (1.0f + expf(-(acc + sb2[0])));
  }
}

extern "C" void kernel_launch(void* const* d_in, const int* in_sizes, int n_in,
                              void* d_out, int out_size, void* d_ws, size_t ws_size,
                              hipStream_t stream) {
  const float* x   = (const float*)d_in[0];
  const void*  ei  = d_in[1];
  const float* W1  = (const float*)d_in[2];
  const float* b1  = (const float*)d_in[3];
  const float* W2  = (const float*)d_in[4];
  const float* b2  = (const float*)d_in[5];
  const float* rW1 = (const float*)d_in[6];
  const float* rb1 = (const float*)d_in[7];
  const float* rW2 = (const float*)d_in[8];
  const float* rb2 = (const float*)d_in[9];
  const float* sW1 = (const float*)d_in[10];
  const float* sb1 = (const float*)d_in[11];
  const float* sW2 = (const float*)d_in[12];
  const float* sb2 = (const float*)d_in[13];

  const int N = in_sizes[0] / 128;
  const int E = in_sizes[1] / 2;

  // bucket geometry: SPB = 1<<shift nodes per bucket, B buckets (<=256)
  int shift = 9;
  while ((((long)N + (1L << shift) - 1) >> shift) > 256) ++shift;
  const int SB = 32 - shift;               // src bits in packed pair
  const int B = (int)(((long)N + (1L << shift) - 1) >> shift);
  const int C = 512;                       // edge chunks
  const int CS = (E + C - 1) / C;          // edges per chunk
  const int L = B * C;

  // workspace layout (256B aligned chunks)
  char* w = (char*)d_ws;
  auto alloc = [&](size_t bytes) {
    char* p = w;
    w += (bytes + 255) & ~(size_t)255;
    return p;
  };
  int*   meta   = (int*)alloc(64);
  int*   cnt    = (int*)alloc((size_t)N * 4);
  int*   rs     = (int*)alloc((size_t)N * 4);
  float* dis    = (float*)alloc((size_t)N * 4);
  int*   bsumsL = (int*)alloc(1024);
  int*   bscan  = (int*)alloc(((size_t)L + 1) * 4);
  int*   csr    = (int*)alloc((size_t)E * 4);
  unsigned* pairs = (unsigned*)alloc((size_t)E * 4);
  uint2* hw1 = (uint2*)alloc((size_t)N * 64 * 2);  // bf16 [N][64]
  uint2* h1  = (uint2*)alloc((size_t)N * 64 * 2);  // bf16 [N][64]
  uint2* hw2 = (uint2*)alloc((size_t)N * 32 * 2);  // bf16 [N][32]

  float* h_out = (float*)d_out;                 // [N,32]
  float* x_rec = h_out + (long)N * 32;          // [N,128]
  float* score = x_rec + (long)N * 128;         // [N,1]

  // ---- CSR build (atomic-free two-level counting sort, lean) ----
  k_detect<<<1, 256, 0, stream>>>((const unsigned int*)ei, E < 4096 ? E : 4096, meta);
  k_binhist<<<C, 256, 0, stream>>>(ei, E, CS, B, shift, meta, bscan, C);
  int nbL = (L + 1023) / 1024;
  k_scan1<<<nbL, 1024, 0, stream>>>(bscan, bsumsL, L);
  k_scan2<<<1, 128, 0, stream>>>(bsumsL, nbL);
  k_scan3s<<<nbL, 1024, 0, stream>>>(bscan, bsumsL, bscan, L, 1);  // in-place + sentinel
  k_binscatter<<<C, 256, 0, stream>>>(ei, E, CS, B, shift, SB, meta, bscan, C, pairs);
  k_bucketbuild<<<B, 256, 0, stream>>>(pairs, bscan, C, shift, SB, N, cnt, dis, rs, csr);

  // ---- layer 1: hw1 = bf16(x @ W1) ; h1 = bf16(relu(agg + b1)) ----
  k_gemm<128, 64, false, 0, false, true><<<(N + 63) / 64, 256, 0, stream>>>(x, W1, nullptr, hw1, N);
  k_agg64p<<<(N + 15) / 16, 256, 0, stream>>>(hw1, csr, rs, cnt, dis, b1, h1, N);

  // ---- layer 2: hw2 = bf16(h1 @ W2) ; h = agg + b2 -> d_out ----
  k_gemm<64, 32, false, 0, true, true><<<(N + 127) / 128, 256, 0, stream>>>(h1, W2, nullptr, hw2, N);
  k_agg32p<<<(N + 31) / 32, 256, 0, stream>>>(hw2, csr, rs, cnt, dis, b2, h_out, N);

  // ---- fused tail: recon MLP + scorer MLP + score ----
  k_tail<<<(N + 63) / 64, 256, 0, stream>>>(h_out, rW1, rb1, rW2, rb2,
                                            sW1, sb1, sW2, sb2, x_rec, score, N);
}

// Round 15
// 281.117 us; speedup vs baseline: 1.0946x; 1.0946x over previous
//
#include <hip/hip_runtime.h>
#include <hip/hip_bf16.h>
#include <math.h>

// ---------------------------------------------------------------------------
// GCN anomaly detector.
// Round 14 post-mortem: deleting bucketbuild's sort REGRESSED (298->308us)
// -- with 196 blocks the 132KB LDS never limited occupancy; reverted.
// Round 15 (base = round-13 298us): (a) GEMM2 fused into agg64 epilogue
// (h1 row staged fp32 in LDS, hw2 = h1@W2 computed in-block; kills GEMM2
// dispatch + 25.6MB h1 round-trip; h1 buffer gone); (b) k_detect folded
// into binhist/binscatter (per-block self-detect on the same 4096 pairs,
// L2-hot). 12 -> 10 dispatches.
// Established floors: agg64 gather 62us @167MB (5 structures tried; traffic
// cuts to 66MB all cost >4x execution); CSR build via atomic-free two-level
// counting sort; fused tail for the 4 per-node tail ops.
// ---------------------------------------------------------------------------

// P1: per-chunk LDS histogram over dst buckets. hist layout: [bin][chunk].
// Self-detects int64 edge_index (high words of first 4096 pairs all zero).
__global__ __launch_bounds__(256) void k_binhist(const void* __restrict__ ei,
                                                 int E, int CS, int B, int shift,
                                                 int ndet,
                                                 int* __restrict__ hist, int C) {
  __shared__ int lh[256];
  __shared__ int s32;
  int t = threadIdx.x;
  if (t == 0) s32 = 0;
  for (int i = t; i < B; i += 256) lh[i] = 0;
  __syncthreads();
  {
    const unsigned* w = (const unsigned*)ei;
    int local = 0;
    for (int i = t; i < ndet; i += 256) local |= (w[2 * i + 1] != 0u);
    if (local) atomicOr(&s32, 1);
  }
  __syncthreads();
  bool is64 = (s32 == 0);
  int c = blockIdx.x;
  int e0 = c * CS, e1 = min(E, e0 + CS);
  for (int e = e0 + t; e < e1; e += 256) {
    int d = is64 ? (int)((const long long*)ei)[(long)E + e]
                 : ((const int*)ei)[(long)E + e];
    atomicAdd(&lh[d >> shift], 1);
  }
  __syncthreads();
  for (int b = t; b < B; b += 256) hist[(long)b * C + c] = lh[b];
}

// P3: re-read edges, write packed (dstInBucket<<SB | src) into reserved
// per-(chunk,bin) ranges. LDS cursors only -> zero global atomics.
__global__ __launch_bounds__(256) void k_binscatter(const void* __restrict__ ei,
                                                    int E, int CS, int B, int shift,
                                                    int SB, int ndet,
                                                    const int* __restrict__ scan,
                                                    int C, unsigned* __restrict__ pairs) {
  __shared__ int cur[256];
  __shared__ int s32;
  int t = threadIdx.x;
  if (t == 0) s32 = 0;
  int c = blockIdx.x;
  for (int b = t; b < B; b += 256) cur[b] = scan[(long)b * C + c];
  __syncthreads();
  {
    const unsigned* w = (const unsigned*)ei;
    int local = 0;
    for (int i = t; i < ndet; i += 256) local |= (w[2 * i + 1] != 0u);
    if (local) atomicOr(&s32, 1);
  }
  __syncthreads();
  bool is64 = (s32 == 0);
  int e0 = c * CS, e1 = min(E, e0 + CS);
  unsigned spb1 = (1u << shift) - 1u;
  for (int e = e0 + t; e < e1; e += 256) {
    int s, d;
    if (is64) {
      const long long* p = (const long long*)ei;
      s = (int)p[e]; d = (int)p[(long)E + e];
    } else {
      const int* p = (const int*)ei;
      s = p[e]; d = p[(long)E + e];
    }
    int pos = atomicAdd(&cur[d >> shift], 1);
    pairs[pos] = (((unsigned)d & spb1) << SB) | (unsigned)s;
  }
}

// P4 (fused): per-bucket degree hist -> cnt, dis, rs; in-LDS counting sort
// by src-bin (measured faster than lean 2-pass-global in R13/R14 A/B);
// scatter via LDS cursors. Overflow falls back to unsorted (still correct).
#define BB_CAP 16896
__global__ __launch_bounds__(256) void k_bucketbuild(const unsigned* __restrict__ pairs,
                                                     const int* __restrict__ scan,
                                                     int C, int shift, int SB, int N,
                                                     int* __restrict__ cnt,
                                                     float* __restrict__ dis,
                                                     int* __restrict__ rs,
                                                     int* __restrict__ csr) {
  __shared__ unsigned buf[BB_CAP];    // 66 KB
  __shared__ unsigned buf2[BB_CAP];   // 66 KB
  __shared__ int h[1024];
  __shared__ int sm[256];
  __shared__ int sh[512];
  int bin = blockIdx.x;
  int base = bin << shift;
  int nn = min(N - base, 1 << shift);
  int t = threadIdx.x;
  unsigned smask = (1u << SB) - 1u;
  int p0 = scan[(long)bin * C];
  int p1 = scan[(long)(bin + 1) * C];  // sentinel row gives E for last bucket
  int ne = p1 - p0;
  bool srt = (ne <= BB_CAP);

  if (srt)
    for (int i = t; i < ne; i += 256) buf[i] = pairs[p0 + i];
  for (int i = t; i < 1024; i += 256) h[i] = 0;
  __syncthreads();

  for (int i = t; i < ne; i += 256)
    atomicAdd(&h[(srt ? buf[i] : pairs[p0 + i]) >> SB], 1);
  __syncthreads();

  int v0 = h[4 * t], v1 = h[4 * t + 1], v2 = h[4 * t + 2], v3 = h[4 * t + 3];
  int s = v0 + v1 + v2 + v3;
  sm[t] = s;
  __syncthreads();
  for (int off = 1; off < 256; off <<= 1) {
    int x = (t >= off) ? sm[t - off] : 0;
    __syncthreads();
    sm[t] += x;
    __syncthreads();
  }
  int run = p0 + sm[t] - s;
  int r0 = run, r1 = run + v0, r2 = r1 + v1, r3 = r2 + v2;
  h[4 * t] = r0; h[4 * t + 1] = r1; h[4 * t + 2] = r2; h[4 * t + 3] = r3;
  if (4 * t + 0 < nn) { cnt[base + 4*t+0] = v0; dis[base + 4*t+0] = rsqrtf((float)v0 + 1.f); rs[base + 4*t+0] = r0; }
  if (4 * t + 1 < nn) { cnt[base + 4*t+1] = v1; dis[base + 4*t+1] = rsqrtf((float)v1 + 1.f); rs[base + 4*t+1] = r1; }
  if (4 * t + 2 < nn) { cnt[base + 4*t+2] = v2; dis[base + 4*t+2] = rsqrtf((float)v2 + 1.f); rs[base + 4*t+2] = r2; }
  if (4 * t + 3 < nn) { cnt[base + 4*t+3] = v3; dis[base + 4*t+3] = rsqrtf((float)v3 + 1.f); rs[base + 4*t+3] = r3; }
  __syncthreads();

  if (srt) {
    for (int i = t; i < 512; i += 256) sh[i] = 0;
    __syncthreads();
    for (int i = t; i < ne; i += 256)
      atomicAdd(&sh[(buf[i] & smask) >> 8], 1);
    __syncthreads();
    int a0 = sh[2 * t], a1 = sh[2 * t + 1];
    int ss = a0 + a1;
    sm[t] = ss;
    __syncthreads();
    for (int off = 1; off < 256; off <<= 1) {
      int x = (t >= off) ? sm[t - off] : 0;
      __syncthreads();
      sm[t] += x;
      __syncthreads();
    }
    int rn = sm[t] - ss;
    sh[2 * t] = rn; sh[2 * t + 1] = rn + a0;
    __syncthreads();
    for (int i = t; i < ne; i += 256) {
      unsigned p = buf[i];
      int pos = atomicAdd(&sh[(p & smask) >> 8], 1);
      buf2[pos] = p;
    }
    __syncthreads();
    for (int i = t; i < ne; i += 256) {
      unsigned p = buf2[i];
      int pos = atomicAdd(&h[p >> SB], 1);
      csr[pos] = (int)(p & smask);
    }
  } else {
    for (int i = p0 + t; i < p1; i += 256) {
      unsigned p = pairs[i];
      int pos = atomicAdd(&h[p >> SB], 1);
      csr[pos] = (int)(p & smask);
    }
  }
}

__global__ __launch_bounds__(1024) void k_scan1(const int* __restrict__ cnt,
                                                int* __restrict__ bsums, int n) {
  __shared__ int sm[1024];
  int t = threadIdx.x;
  long i = (long)blockIdx.x * 1024 + t;
  sm[t] = (i < n) ? cnt[i] : 0;
  __syncthreads();
  for (int s = 512; s > 0; s >>= 1) {
    if (t < s) sm[t] += sm[t + s];
    __syncthreads();
  }
  if (t == 0) bsums[blockIdx.x] = sm[0];
}

__global__ void k_scan2(int* __restrict__ bsums, int nb) {
  __shared__ int sm[128];
  int t = threadIdx.x;
  int v = (t < nb) ? bsums[t] : 0;
  sm[t] = v;
  __syncthreads();
  for (int off = 1; off < 128; off <<= 1) {
    int x = (t >= off) ? sm[t - off] : 0;
    __syncthreads();
    sm[t] += x;
    __syncthreads();
  }
  if (t < nb) bsums[t] = sm[t] - v;  // exclusive
}

// exclusive scan -> out (may alias in); optional sentinel out[n] = total.
__global__ __launch_bounds__(1024) void k_scan3s(const int* __restrict__ in,
                                                 const int* __restrict__ bsums,
                                                 int* __restrict__ out, int n,
                                                 int sentinel) {
  __shared__ int sm[1024];
  int t = threadIdx.x;
  long i = (long)blockIdx.x * 1024 + t;
  int v = (i < n) ? in[i] : 0;
  sm[t] = v;
  __syncthreads();
  for (int off = 1; off < 1024; off <<= 1) {
    int x = (t >= off) ? sm[t - off] : 0;
    __syncthreads();
    sm[t] += x;
    __syncthreads();
  }
  int excl = sm[t] - v + bsums[blockIdx.x];
  if (i < n) out[i] = excl;
  if (sentinel && i == n - 1) out[n] = excl + v;
}

__device__ __forceinline__ float bfu(unsigned short u) {
  return __uint_as_float((unsigned)u << 16);
}
__device__ __forceinline__ float bf_lo(unsigned u) {
  return __uint_as_float(u << 16);
}
__device__ __forceinline__ float bf_hi(unsigned u) {
  return __uint_as_float(u & 0xffff0000u);
}
__device__ __forceinline__ unsigned pack_bf2(float lo, float hi) {
  __hip_bfloat16 a = __float2bfloat16(lo), b = __float2bfloat16(hi);
  return (unsigned)*(unsigned short*)&a | ((unsigned)*(unsigned short*)&b << 16);
}

// C[n, M] = act(A[n, K] @ W[K, M] (+ bias)); W row-major [K][M], staged in LDS.
// K-loop pinned to no-unroll + manual next-k prefetch.
// ABF16: A rows are bf16. OBF16: write output as bf16 (RNE).
template <int K, int M, bool BIAS, int ACT, bool ABF16, bool OBF16>
__global__ __launch_bounds__(256) void k_gemm(const void* __restrict__ Av,
                                              const float* __restrict__ W,
                                              const float* __restrict__ bias,
                                              void* __restrict__ Cout, int nrows) {
  constexpr int CP = 4;
  constexpr int TPR = M / CP;        // threads per row
  constexpr int RG = 256 / TPR;      // row-groups per block
  constexpr int RP = 4;              // rows per thread
  constexpr int RT = RG * RP;        // rows per block
  __shared__ __align__(16) float sW[K * M];
  __shared__ __align__(16) float sB[BIAS ? M : 4];

  for (int i = threadIdx.x; i < K * M / 4; i += 256)
    ((float4*)sW)[i] = ((const float4*)W)[i];
  if (BIAS)
    for (int i = threadIdx.x; i < M; i += 256) sB[i] = bias[i];
  __syncthreads();

  const int cg = threadIdx.x % TPR;
  const int rg = threadIdx.x / TPR;
  const long row0 = (long)blockIdx.x * RT + rg;

  const float4* Apf[RP];
  const ushort4* Apb[RP];
  bool valid[RP];
#pragma unroll
  for (int r = 0; r < RP; ++r) {
    long row = row0 + (long)r * RG;
    valid[r] = (row < nrows);
    long rr = valid[r] ? row : 0;
    if (ABF16) Apb[r] = (const ushort4*)((const unsigned short*)Av + rr * K);
    else       Apf[r] = (const float4*)((const float*)Av + rr * K);
  }

  auto loadA = [&](int r, int k4) -> float4 {
    if (!valid[r]) return make_float4(0.f, 0.f, 0.f, 0.f);
    if (ABF16) {
      ushort4 q = Apb[r][k4];
      return make_float4(bfu(q.x), bfu(q.y), bfu(q.z), bfu(q.w));
    }
    return Apf[r][k4];
  };

  float acc[RP][CP] = {};
  float4 a[RP];
#pragma unroll
  for (int r = 0; r < RP; ++r) a[r] = loadA(r, 0);

#pragma unroll 1
  for (int k0 = 0; k0 < K - 4; k0 += 4) {
    float4 an[RP];
#pragma unroll
    for (int r = 0; r < RP; ++r) an[r] = loadA(r, k0 / 4 + 1);
#pragma unroll
    for (int j = 0; j < 4; ++j) {
      float4 w = ((const float4*)(sW + (k0 + j) * M))[cg];
#pragma unroll
      for (int r = 0; r < RP; ++r) {
        float av = (j == 0) ? a[r].x : (j == 1) ? a[r].y : (j == 2) ? a[r].z : a[r].w;
        acc[r][0] += av * w.x;
        acc[r][1] += av * w.y;
        acc[r][2] += av * w.z;
        acc[r][3] += av * w.w;
      }
    }
#pragma unroll
    for (int r = 0; r < RP; ++r) a[r] = an[r];
  }
  {  // last k-step
    const int k0 = K - 4;
#pragma unroll
    for (int j = 0; j < 4; ++j) {
      float4 w = ((const float4*)(sW + (k0 + j) * M))[cg];
#pragma unroll
      for (int r = 0; r < RP; ++r) {
        float av = (j == 0) ? a[r].x : (j == 1) ? a[r].y : (j == 2) ? a[r].z : a[r].w;
        acc[r][0] += av * w.x;
        acc[r][1] += av * w.y;
        acc[r][2] += av * w.z;
        acc[r][3] += av * w.w;
      }
    }
  }

#pragma unroll
  for (int r = 0; r < RP; ++r) {
    long row = row0 + (long)r * RG;
    if (row >= nrows) continue;
    float4 o = make_float4(acc[r][0], acc[r][1], acc[r][2], acc[r][3]);
    if (BIAS) {
      float4 bb = ((const float4*)sB)[cg];
      o.x += bb.x; o.y += bb.y; o.z += bb.z; o.w += bb.w;
    }
    if (ACT == 1) {
      o.x = fmaxf(o.x, 0.f); o.y = fmaxf(o.y, 0.f);
      o.z = fmaxf(o.z, 0.f); o.w = fmaxf(o.w, 0.f);
    }
    if (OBF16) {
      uint2 pk;
      pk.x = pack_bf2(o.x, o.y);
      pk.y = pack_bf2(o.z, o.w);
      ((uint2*)((__hip_bfloat16*)Cout + row * M))[cg] = pk;
    } else {
      ((float4*)((float*)Cout + row * M))[cg] = o;
    }
  }
}

// Fused agg64 + GEMM2: gather h1 row (fp32, registers) per node, stage in
// LDS, then hw2 = h1 @ W2 (bf16 out) in the same block. 16 lanes/node,
// 16 nodes/block, unroll 8 gather.
__global__ __launch_bounds__(256) void k_agg64g(const uint2* __restrict__ hw,
                                                const int* __restrict__ csr,
                                                const int* __restrict__ rs,
                                                const int* __restrict__ cnt,
                                                const float* __restrict__ dis,
                                                const float* __restrict__ b,
                                                const float* __restrict__ W2,
                                                unsigned* __restrict__ hw2,
                                                int n) {
  __shared__ __align__(16) float sW2[64 * 32];  // 8 KB
  __shared__ __align__(16) float sH[16][68];    // 4.25 KB, padded stride
  int t = threadIdx.x;
  for (int i = t; i < 64 * 32 / 4; i += 256)
    ((float4*)sW2)[i] = ((const float4*)W2)[i];

  unsigned nd = t >> 4;
  unsigned node = blockIdx.x * 16u + nd;
  unsigned f4 = t & 15;
  bool ok = (node < (unsigned)n);
  float o0 = 0.f, o1 = 0.f, o2 = 0.f, o3 = 0.f;
  if (ok) {
    float dsn = dis[node];
    uint2 su = hw[node * 16u + f4];
    float d2 = dsn * dsn;
    float a0 = bf_lo(su.x) * d2, a1 = bf_hi(su.x) * d2;
    float a2 = bf_lo(su.y) * d2, a3 = bf_hi(su.y) * d2;
    int start = rs[node], deg = cnt[node];
    int e = 0;
    for (; e + 7 < deg; e += 8) {
      unsigned s0 = (unsigned)csr[start + e];
      unsigned s1 = (unsigned)csr[start + e + 1];
      unsigned s2 = (unsigned)csr[start + e + 2];
      unsigned s3 = (unsigned)csr[start + e + 3];
      unsigned s4 = (unsigned)csr[start + e + 4];
      unsigned s5 = (unsigned)csr[start + e + 5];
      unsigned s6 = (unsigned)csr[start + e + 6];
      unsigned s7 = (unsigned)csr[start + e + 7];
      float w0 = dis[s0] * dsn, w1 = dis[s1] * dsn;
      float w2 = dis[s2] * dsn, w3 = dis[s3] * dsn;
      float w4 = dis[s4] * dsn, w5 = dis[s5] * dsn;
      float w6 = dis[s6] * dsn, w7 = dis[s7] * dsn;
      uint2 u0 = hw[s0 * 16u + f4];
      uint2 u1 = hw[s1 * 16u + f4];
      uint2 u2 = hw[s2 * 16u + f4];
      uint2 u3 = hw[s3 * 16u + f4];
      uint2 u4 = hw[s4 * 16u + f4];
      uint2 u5 = hw[s5 * 16u + f4];
      uint2 u6 = hw[s6 * 16u + f4];
      uint2 u7 = hw[s7 * 16u + f4];
      a0 += bf_lo(u0.x) * w0 + bf_lo(u1.x) * w1 + bf_lo(u2.x) * w2 + bf_lo(u3.x) * w3
          + bf_lo(u4.x) * w4 + bf_lo(u5.x) * w5 + bf_lo(u6.x) * w6 + bf_lo(u7.x) * w7;
      a1 += bf_hi(u0.x) * w0 + bf_hi(u1.x) * w1 + bf_hi(u2.x) * w2 + bf_hi(u3.x) * w3
          + bf_hi(u4.x) * w4 + bf_hi(u5.x) * w5 + bf_hi(u6.x) * w6 + bf_hi(u7.x) * w7;
      a2 += bf_lo(u0.y) * w0 + bf_lo(u1.y) * w1 + bf_lo(u2.y) * w2 + bf_lo(u3.y) * w3
          + bf_lo(u4.y) * w4 + bf_lo(u5.y) * w5 + bf_lo(u6.y) * w6 + bf_lo(u7.y) * w7;
      a3 += bf_hi(u0.y) * w0 + bf_hi(u1.y) * w1 + bf_hi(u2.y) * w2 + bf_hi(u3.y) * w3
          + bf_hi(u4.y) * w4 + bf_hi(u5.y) * w5 + bf_hi(u6.y) * w6 + bf_hi(u7.y) * w7;
    }
    for (; e < deg; ++e) {
      unsigned s0 = (unsigned)csr[start + e];
      float w0 = dis[s0] * dsn;
      uint2 u0 = hw[s0 * 16u + f4];
      a0 += bf_lo(u0.x) * w0;
      a1 += bf_hi(u0.x) * w0;
      a2 += bf_lo(u0.y) * w0;
      a3 += bf_hi(u0.y) * w0;
    }
    float4 bb = ((const float4*)b)[f4];
    o0 = fmaxf(a0 + bb.x, 0.f);  // relu(agg + b1) = h1, fp32
    o1 = fmaxf(a1 + bb.y, 0.f);
    o2 = fmaxf(a2 + bb.z, 0.f);
    o3 = fmaxf(a3 + bb.w, 0.f);
  }
  ((float4*)&sH[nd][4 * f4])[0] = make_float4(o0, o1, o2, o3);
  __syncthreads();
  if (ok) {
    // hw2[node][2*f4 .. 2*f4+1] = sum_k h1[k] * W2[k][2*f4 ..]
    float acc0 = 0.f, acc1 = 0.f;
#pragma unroll 8
    for (int k = 0; k < 64; ++k) {
      float hv = sH[nd][k];
      float2 w = *(const float2*)(sW2 + k * 32 + 2 * f4);
      acc0 += hv * w.x;
      acc1 += hv * w.y;
    }
    hw2[node * 16u + f4] = pack_bf2(acc0, acc1);
  }
}

// Pull aggregation, D=32 bf16: 8 lanes/node (4 feats = uint2 per lane),
// 8 nodes/wave, unroll 8. fp32 output (this IS the h output in d_out).
__global__ __launch_bounds__(256) void k_agg32p(const uint2* __restrict__ hw,
                                                const int* __restrict__ csr,
                                                const int* __restrict__ rs,
                                                const int* __restrict__ cnt,
                                                const float* __restrict__ dis,
                                                const float* __restrict__ b,
                                                float* __restrict__ out, int n) {
  unsigned node = blockIdx.x * 32u + (threadIdx.x >> 3);
  if (node >= (unsigned)n) return;
  unsigned f4 = threadIdx.x & 7;
  float dsn = dis[node];
  uint2 su = hw[node * 8u + f4];
  float d2 = dsn * dsn;
  float a0 = bf_lo(su.x) * d2, a1 = bf_hi(su.x) * d2;
  float a2 = bf_lo(su.y) * d2, a3 = bf_hi(su.y) * d2;
  int start = rs[node], deg = cnt[node];
  int e = 0;
  for (; e + 7 < deg; e += 8) {
    unsigned s0 = (unsigned)csr[start + e];
    unsigned s1 = (unsigned)csr[start + e + 1];
    unsigned s2 = (unsigned)csr[start + e + 2];
    unsigned s3 = (unsigned)csr[start + e + 3];
    unsigned s4 = (unsigned)csr[start + e + 4];
    unsigned s5 = (unsigned)csr[start + e + 5];
    unsigned s6 = (unsigned)csr[start + e + 6];
    unsigned s7 = (unsigned)csr[start + e + 7];
    float w0 = dis[s0] * dsn, w1 = dis[s1] * dsn;
    float w2 = dis[s2] * dsn, w3 = dis[s3] * dsn;
    float w4 = dis[s4] * dsn, w5 = dis[s5] * dsn;
    float w6 = dis[s6] * dsn, w7 = dis[s7] * dsn;
    uint2 u0 = hw[s0 * 8u + f4];
    uint2 u1 = hw[s1 * 8u + f4];
    uint2 u2 = hw[s2 * 8u + f4];
    uint2 u3 = hw[s3 * 8u + f4];
    uint2 u4 = hw[s4 * 8u + f4];
    uint2 u5 = hw[s5 * 8u + f4];
    uint2 u6 = hw[s6 * 8u + f4];
    uint2 u7 = hw[s7 * 8u + f4];
    a0 += bf_lo(u0.x) * w0 + bf_lo(u1.x) * w1 + bf_lo(u2.x) * w2 + bf_lo(u3.x) * w3
        + bf_lo(u4.x) * w4 + bf_lo(u5.x) * w5 + bf_lo(u6.x) * w6 + bf_lo(u7.x) * w7;
    a1 += bf_hi(u0.x) * w0 + bf_hi(u1.x) * w1 + bf_hi(u2.x) * w2 + bf_hi(u3.x) * w3
        + bf_hi(u4.x) * w4 + bf_hi(u5.x) * w5 + bf_hi(u6.x) * w6 + bf_hi(u7.x) * w7;
    a2 += bf_lo(u0.y) * w0 + bf_lo(u1.y) * w1 + bf_lo(u2.y) * w2 + bf_lo(u3.y) * w3
        + bf_lo(u4.y) * w4 + bf_lo(u5.y) * w5 + bf_lo(u6.y) * w6 + bf_lo(u7.y) * w7;
    a3 += bf_hi(u0.y) * w0 + bf_hi(u1.y) * w1 + bf_hi(u2.y) * w2 + bf_hi(u3.y) * w3
        + bf_hi(u4.y) * w4 + bf_hi(u5.y) * w5 + bf_hi(u6.y) * w6 + bf_hi(u7.y) * w7;
  }
  for (; e < deg; ++e) {
    unsigned s0 = (unsigned)csr[start + e];
    float w0 = dis[s0] * dsn;
    uint2 u0 = hw[s0 * 8u + f4];
    a0 += bf_lo(u0.x) * w0;
    a1 += bf_hi(u0.x) * w0;
    a2 += bf_lo(u0.y) * w0;
    a3 += bf_hi(u0.y) * w0;
  }
  float4 bb = ((const float4*)b)[f4];
  ((float4*)(out + node * 32u))[f4] =
      make_float4(a0 + bb.x, a1 + bb.y, a2 + bb.z, a3 + bb.w);
}

// Fused tail: per block of 64 nodes, from h (fp32 [N,32] in d_out):
//   t = relu(h@rW1+rb1) (LDS) ; x_rec = t@rW2+rb2 -> global
//   s = relu(h@sW1+sb1) (LDS) ; score = sigmoid(s.sW2+sb2) -> global
// Padded LDS strides (33/65) kill bank conflicts on row-indexed reads.
__global__ __launch_bounds__(256) void k_tail(const float* __restrict__ h,
                                              const float* __restrict__ rW1,
                                              const float* __restrict__ rb1,
                                              const float* __restrict__ rW2,
                                              const float* __restrict__ rb2,
                                              const float* __restrict__ sW1,
                                              const float* __restrict__ sb1,
                                              const float* __restrict__ sW2,
                                              const float* __restrict__ sb2,
                                              float* __restrict__ x_rec,
                                              float* __restrict__ score, int n) {
  __shared__ __align__(16) float sRW1[32 * 64];    // 8 KB
  __shared__ __align__(16) float sRW2[64 * 128];   // 32 KB
  __shared__ __align__(16) float sSW1[32 * 32];    // 4 KB
  __shared__ __align__(16) float sRB1[64];
  __shared__ __align__(16) float sRB2[128];
  __shared__ __align__(16) float sSB1[32];
  __shared__ __align__(16) float sSW2[32];
  __shared__ float sH[64 * 33];                    // 8.45 KB
  __shared__ float sT[64 * 65];                    // 16.6 KB
  __shared__ float sS[64 * 33];                    // 8.45 KB
  int t = threadIdx.x;
  for (int i = t; i < 32 * 64 / 4; i += 256) ((float4*)sRW1)[i] = ((const float4*)rW1)[i];
  for (int i = t; i < 64 * 128 / 4; i += 256) ((float4*)sRW2)[i] = ((const float4*)rW2)[i];
  for (int i = t; i < 32 * 32 / 4; i += 256) ((float4*)sSW1)[i] = ((const float4*)sW1)[i];
  if (t < 64) sRB1[t] = rb1[t];
  else if (t < 192) sRB2[t - 64] = rb2[t - 64];
  else if (t < 224) sSB1[t - 192] = sb1[t - 192];
  else sSW2[t - 224] = sW2[t - 224];

  long base = (long)blockIdx.x * 64;
  int nn = (int)min(64L, (long)n - base);
  if (nn < 0) nn = 0;
  for (int i = t; i < 64 * 8; i += 256) {          // 512 float4 loads of h
    int node = i >> 3, q = i & 7;
    float4 v = (node < nn) ? ((const float4*)(h + (base + node) * 32))[q]
                           : make_float4(0.f, 0.f, 0.f, 0.f);
    sH[node * 33 + 4 * q]     = v.x;
    sH[node * 33 + 4 * q + 1] = v.y;
    sH[node * 33 + 4 * q + 2] = v.z;
    sH[node * 33 + 4 * q + 3] = v.w;
  }
  __syncthreads();

  {  // phase T: M=64, TPR=16, RG=16, RP=4
    int cg = t & 15, rg = t >> 4;
    float acc[4][4] = {};
    for (int k = 0; k < 32; ++k) {
      float4 w = ((const float4*)(sRW1 + k * 64))[cg];
      float a0 = sH[rg * 33 + k];
      float a1 = sH[(rg + 16) * 33 + k];
      float a2 = sH[(rg + 32) * 33 + k];
      float a3 = sH[(rg + 48) * 33 + k];
      acc[0][0] += a0 * w.x; acc[0][1] += a0 * w.y; acc[0][2] += a0 * w.z; acc[0][3] += a0 * w.w;
      acc[1][0] += a1 * w.x; acc[1][1] += a1 * w.y; acc[1][2] += a1 * w.z; acc[1][3] += a1 * w.w;
      acc[2][0] += a2 * w.x; acc[2][1] += a2 * w.y; acc[2][2] += a2 * w.z; acc[2][3] += a2 * w.w;
      acc[3][0] += a3 * w.x; acc[3][1] += a3 * w.y; acc[3][2] += a3 * w.z; acc[3][3] += a3 * w.w;
    }
    float4 bb = ((const float4*)sRB1)[cg];
#pragma unroll
    for (int m = 0; m < 4; ++m) {
      int row = rg + 16 * m;
      sT[row * 65 + 4 * cg]     = fmaxf(acc[m][0] + bb.x, 0.f);
      sT[row * 65 + 4 * cg + 1] = fmaxf(acc[m][1] + bb.y, 0.f);
      sT[row * 65 + 4 * cg + 2] = fmaxf(acc[m][2] + bb.z, 0.f);
      sT[row * 65 + 4 * cg + 3] = fmaxf(acc[m][3] + bb.w, 0.f);
    }
  }
  {  // phase S: M=32, TPR=8, RG=32, RP=2
    int cg = t & 7, rg = t >> 3;
    float acc[2][4] = {};
    for (int k = 0; k < 32; ++k) {
      float4 w = ((const float4*)(sSW1 + k * 32))[cg];
      float a0 = sH[rg * 33 + k];
      float a1 = sH[(rg + 32) * 33 + k];
      acc[0][0] += a0 * w.x; acc[0][1] += a0 * w.y; acc[0][2] += a0 * w.z; acc[0][3] += a0 * w.w;
      acc[1][0] += a1 * w.x; acc[1][1] += a1 * w.y; acc[1][2] += a1 * w.z; acc[1][3] += a1 * w.w;
    }
    float4 bb = ((const float4*)sSB1)[cg];
#pragma unroll
    for (int m = 0; m < 2; ++m) {
      int row = rg + 32 * m;
      sS[row * 33 + 4 * cg]     = fmaxf(acc[m][0] + bb.x, 0.f);
      sS[row * 33 + 4 * cg + 1] = fmaxf(acc[m][1] + bb.y, 0.f);
      sS[row * 33 + 4 * cg + 2] = fmaxf(acc[m][2] + bb.z, 0.f);
      sS[row * 33 + 4 * cg + 3] = fmaxf(acc[m][3] + bb.w, 0.f);
    }
  }
  __syncthreads();

  {  // phase X: M=128, TPR=32, RG=8, RP=8 -> x_rec global
    int cg = t & 31, rg = t >> 5;
    float acc[8][4] = {};
    for (int k = 0; k < 64; ++k) {
      float4 w = ((const float4*)(sRW2 + k * 128))[cg];
#pragma unroll
      for (int m = 0; m < 8; ++m) {
        float a = sT[(rg + 8 * m) * 65 + k];
        acc[m][0] += a * w.x; acc[m][1] += a * w.y;
        acc[m][2] += a * w.z; acc[m][3] += a * w.w;
      }
    }
    float4 bb = ((const float4*)sRB2)[cg];
#pragma unroll
    for (int m = 0; m < 8; ++m) {
      int row = rg + 8 * m;
      if (row < nn) {
        float4 o = make_float4(acc[m][0] + bb.x, acc[m][1] + bb.y,
                               acc[m][2] + bb.z, acc[m][3] + bb.w);
        ((float4*)(x_rec + (base + row) * 128))[cg] = o;
      }
    }
  }
  if (t < nn) {  // score: one thread per node
    float acc = 0.f;
    for (int j = 0; j < 32; ++j) acc += sS[t * 33 + j] * sSW2[j];
    score[base + t] = 1.0f / (1.0f + expf(-(acc + sb2[0])));
  }
}

extern "C" void kernel_launch(void* const* d_in, const int* in_sizes, int n_in,
                              void* d_out, int out_size, void* d_ws, size_t ws_size,
                              hipStream_t stream) {
  const float* x   = (const float*)d_in[0];
  const void*  ei  = d_in[1];
  const float* W1  = (const float*)d_in[2];
  const float* b1  = (const float*)d_in[3];
  const float* W2  = (const float*)d_in[4];
  const float* b2  = (const float*)d_in[5];
  const float* rW1 = (const float*)d_in[6];
  const float* rb1 = (const float*)d_in[7];
  const float* rW2 = (const float*)d_in[8];
  const float* rb2 = (const float*)d_in[9];
  const float* sW1 = (const float*)d_in[10];
  const float* sb1 = (const float*)d_in[11];
  const float* sW2 = (const float*)d_in[12];
  const float* sb2 = (const float*)d_in[13];

  const int N = in_sizes[0] / 128;
  const int E = in_sizes[1] / 2;
  const int ndet = E < 4096 ? E : 4096;

  // bucket geometry: SPB = 1<<shift nodes per bucket, B buckets (<=256)
  int shift = 9;
  while ((((long)N + (1L << shift) - 1) >> shift) > 256) ++shift;
  const int SB = 32 - shift;               // src bits in packed pair
  const int B = (int)(((long)N + (1L << shift) - 1) >> shift);
  const int C = 512;                       // edge chunks
  const int CS = (E + C - 1) / C;          // edges per chunk
  const int L = B * C;

  // workspace layout (256B aligned chunks)
  char* w = (char*)d_ws;
  auto alloc = [&](size_t bytes) {
    char* p = w;
    w += (bytes + 255) & ~(size_t)255;
    return p;
  };
  int*   cnt    = (int*)alloc((size_t)N * 4);
  int*   rs     = (int*)alloc((size_t)N * 4);
  float* dis    = (float*)alloc((size_t)N * 4);
  int*   bsumsL = (int*)alloc(1024);
  int*   bscan  = (int*)alloc(((size_t)L + 1) * 4);
  int*   csr    = (int*)alloc((size_t)E * 4);
  unsigned* pairs = (unsigned*)alloc((size_t)E * 4);
  uint2* hw1 = (uint2*)alloc((size_t)N * 64 * 2);  // bf16 [N][64]
  unsigned* hw2 = (unsigned*)alloc((size_t)N * 32 * 2);  // bf16 [N][32]

  float* h_out = (float*)d_out;                 // [N,32]
  float* x_rec = h_out + (long)N * 32;          // [N,128]
  float* score = x_rec + (long)N * 128;         // [N,1]

  // ---- CSR build (atomic-free two-level counting sort; self-detecting) ----
  k_binhist<<<C, 256, 0, stream>>>(ei, E, CS, B, shift, ndet, bscan, C);
  int nbL = (L + 1023) / 1024;
  k_scan1<<<nbL, 1024, 0, stream>>>(bscan, bsumsL, L);
  k_scan2<<<1, 128, 0, stream>>>(bsumsL, nbL);
  k_scan3s<<<nbL, 1024, 0, stream>>>(bscan, bsumsL, bscan, L, 1);  // in-place + sentinel
  k_binscatter<<<C, 256, 0, stream>>>(ei, E, CS, B, shift, SB, ndet, bscan, C, pairs);
  k_bucketbuild<<<B, 256, 0, stream>>>(pairs, bscan, C, shift, SB, N, cnt, dis, rs, csr);

  // ---- layer 1 + GEMM2 fused: hw1 = bf16(x @ W1) ;
  //      h1 = relu(agg + b1) (fp32, LDS-only) ; hw2 = bf16(h1 @ W2) ----
  k_gemm<128, 64, false, 0, false, true><<<(N + 63) / 64, 256, 0, stream>>>(x, W1, nullptr, hw1, N);
  k_agg64g<<<(N + 15) / 16, 256, 0, stream>>>(hw1, csr, rs, cnt, dis, b1, W2, hw2, N);

  // ---- layer 2 agg: h = agg + b2 -> d_out ----
  k_agg32p<<<(N + 31) / 32, 256, 0, stream>>>((const uint2*)hw2, csr, rs, cnt, dis, b2, h_out, N);

  // ---- fused tail: recon MLP + scorer MLP + score ----
  k_tail<<<(N + 63) / 64, 256, 0, stream>>>(h_out, rW1, rb1, rW2, rb2,
                                            sW1, sb1, sW2, sb2, x_rec, score, N);
}

// Round 16
// 264.127 us; speedup vs baseline: 1.1650x; 1.0643x over previous
//
#include <hip/hip_runtime.h>
#include <hip/hip_bf16.h>
#include <math.h>

// ---------------------------------------------------------------------------
// GCN anomaly detector.
// Round 15 landed GEMM2-into-agg64 fusion (298->281us). Round 16: fuse
// agg32 + tail into k_aggtail, PRESERVING agg32p's gather occupancy
// (32 nodes/block, 8 lanes/node, ~30KB LDS -> 5 blocks/CU): gather h in
// registers -> write global h (output) + LDS copy -> in-block tail MLPs
// (t/s in LDS; rW2 read from global: block-broadcast, L2-resident).
// Kills the tail kernel's 12.8MB h re-read + weight staging + 1 launch.
// Established floors: agg64 gather 62us @167MB (5 alt structures all
// worse); CSR build atomic-free two-level counting sort; bucketbuild's
// in-LDS sort variant measured faster than lean 2-pass (R13/R14 A/B).
// ---------------------------------------------------------------------------

// P1: per-chunk LDS histogram over dst buckets. hist layout: [bin][chunk].
// Self-detects int64 edge_index (high words of first ndet pairs all zero).
__global__ __launch_bounds__(256) void k_binhist(const void* __restrict__ ei,
                                                 int E, int CS, int B, int shift,
                                                 int ndet,
                                                 int* __restrict__ hist, int C) {
  __shared__ int lh[256];
  __shared__ int s32;
  int t = threadIdx.x;
  if (t == 0) s32 = 0;
  for (int i = t; i < B; i += 256) lh[i] = 0;
  __syncthreads();
  {
    const unsigned* w = (const unsigned*)ei;
    int local = 0;
    for (int i = t; i < ndet; i += 256) local |= (w[2 * i + 1] != 0u);
    if (local) atomicOr(&s32, 1);
  }
  __syncthreads();
  bool is64 = (s32 == 0);
  int c = blockIdx.x;
  int e0 = c * CS, e1 = min(E, e0 + CS);
  for (int e = e0 + t; e < e1; e += 256) {
    int d = is64 ? (int)((const long long*)ei)[(long)E + e]
                 : ((const int*)ei)[(long)E + e];
    atomicAdd(&lh[d >> shift], 1);
  }
  __syncthreads();
  for (int b = t; b < B; b += 256) hist[(long)b * C + c] = lh[b];
}

// P3: re-read edges, write packed (dstInBucket<<SB | src) into reserved
// per-(chunk,bin) ranges. LDS cursors only -> zero global atomics.
__global__ __launch_bounds__(256) void k_binscatter(const void* __restrict__ ei,
                                                    int E, int CS, int B, int shift,
                                                    int SB, int ndet,
                                                    const int* __restrict__ scan,
                                                    int C, unsigned* __restrict__ pairs) {
  __shared__ int cur[256];
  __shared__ int s32;
  int t = threadIdx.x;
  if (t == 0) s32 = 0;
  int c = blockIdx.x;
  for (int b = t; b < B; b += 256) cur[b] = scan[(long)b * C + c];
  __syncthreads();
  {
    const unsigned* w = (const unsigned*)ei;
    int local = 0;
    for (int i = t; i < ndet; i += 256) local |= (w[2 * i + 1] != 0u);
    if (local) atomicOr(&s32, 1);
  }
  __syncthreads();
  bool is64 = (s32 == 0);
  int e0 = c * CS, e1 = min(E, e0 + CS);
  unsigned spb1 = (1u << shift) - 1u;
  for (int e = e0 + t; e < e1; e += 256) {
    int s, d;
    if (is64) {
      const long long* p = (const long long*)ei;
      s = (int)p[e]; d = (int)p[(long)E + e];
    } else {
      const int* p = (const int*)ei;
      s = p[e]; d = p[(long)E + e];
    }
    int pos = atomicAdd(&cur[d >> shift], 1);
    pairs[pos] = (((unsigned)d & spb1) << SB) | (unsigned)s;
  }
}

// P4 (fused): per-bucket degree hist -> cnt, dis, rs; in-LDS counting sort
// by src-bin (measured faster than lean 2-pass-global in R13/R14 A/B);
// scatter via LDS cursors. Overflow falls back to unsorted (still correct).
#define BB_CAP 16896
__global__ __launch_bounds__(256) void k_bucketbuild(const unsigned* __restrict__ pairs,
                                                     const int* __restrict__ scan,
                                                     int C, int shift, int SB, int N,
                                                     int* __restrict__ cnt,
                                                     float* __restrict__ dis,
                                                     int* __restrict__ rs,
                                                     int* __restrict__ csr) {
  __shared__ unsigned buf[BB_CAP];    // 66 KB
  __shared__ unsigned buf2[BB_CAP];   // 66 KB
  __shared__ int h[1024];
  __shared__ int sm[256];
  __shared__ int sh[512];
  int bin = blockIdx.x;
  int base = bin << shift;
  int nn = min(N - base, 1 << shift);
  int t = threadIdx.x;
  unsigned smask = (1u << SB) - 1u;
  int p0 = scan[(long)bin * C];
  int p1 = scan[(long)(bin + 1) * C];  // sentinel row gives E for last bucket
  int ne = p1 - p0;
  bool srt = (ne <= BB_CAP);

  if (srt)
    for (int i = t; i < ne; i += 256) buf[i] = pairs[p0 + i];
  for (int i = t; i < 1024; i += 256) h[i] = 0;
  __syncthreads();

  for (int i = t; i < ne; i += 256)
    atomicAdd(&h[(srt ? buf[i] : pairs[p0 + i]) >> SB], 1);
  __syncthreads();

  int v0 = h[4 * t], v1 = h[4 * t + 1], v2 = h[4 * t + 2], v3 = h[4 * t + 3];
  int s = v0 + v1 + v2 + v3;
  sm[t] = s;
  __syncthreads();
  for (int off = 1; off < 256; off <<= 1) {
    int x = (t >= off) ? sm[t - off] : 0;
    __syncthreads();
    sm[t] += x;
    __syncthreads();
  }
  int run = p0 + sm[t] - s;
  int r0 = run, r1 = run + v0, r2 = r1 + v1, r3 = r2 + v2;
  h[4 * t] = r0; h[4 * t + 1] = r1; h[4 * t + 2] = r2; h[4 * t + 3] = r3;
  if (4 * t + 0 < nn) { cnt[base + 4*t+0] = v0; dis[base + 4*t+0] = rsqrtf((float)v0 + 1.f); rs[base + 4*t+0] = r0; }
  if (4 * t + 1 < nn) { cnt[base + 4*t+1] = v1; dis[base + 4*t+1] = rsqrtf((float)v1 + 1.f); rs[base + 4*t+1] = r1; }
  if (4 * t + 2 < nn) { cnt[base + 4*t+2] = v2; dis[base + 4*t+2] = rsqrtf((float)v2 + 1.f); rs[base + 4*t+2] = r2; }
  if (4 * t + 3 < nn) { cnt[base + 4*t+3] = v3; dis[base + 4*t+3] = rsqrtf((float)v3 + 1.f); rs[base + 4*t+3] = r3; }
  __syncthreads();

  if (srt) {
    for (int i = t; i < 512; i += 256) sh[i] = 0;
    __syncthreads();
    for (int i = t; i < ne; i += 256)
      atomicAdd(&sh[(buf[i] & smask) >> 8], 1);
    __syncthreads();
    int a0 = sh[2 * t], a1 = sh[2 * t + 1];
    int ss = a0 + a1;
    sm[t] = ss;
    __syncthreads();
    for (int off = 1; off < 256; off <<= 1) {
      int x = (t >= off) ? sm[t - off] : 0;
      __syncthreads();
      sm[t] += x;
      __syncthreads();
    }
    int rn = sm[t] - ss;
    sh[2 * t] = rn; sh[2 * t + 1] = rn + a0;
    __syncthreads();
    for (int i = t; i < ne; i += 256) {
      unsigned p = buf[i];
      int pos = atomicAdd(&sh[(p & smask) >> 8], 1);
      buf2[pos] = p;
    }
    __syncthreads();
    for (int i = t; i < ne; i += 256) {
      unsigned p = buf2[i];
      int pos = atomicAdd(&h[p >> SB], 1);
      csr[pos] = (int)(p & smask);
    }
  } else {
    for (int i = p0 + t; i < p1; i += 256) {
      unsigned p = pairs[i];
      int pos = atomicAdd(&h[p >> SB], 1);
      csr[pos] = (int)(p & smask);
    }
  }
}

__global__ __launch_bounds__(1024) void k_scan1(const int* __restrict__ cnt,
                                                int* __restrict__ bsums, int n) {
  __shared__ int sm[1024];
  int t = threadIdx.x;
  long i = (long)blockIdx.x * 1024 + t;
  sm[t] = (i < n) ? cnt[i] : 0;
  __syncthreads();
  for (int s = 512; s > 0; s >>= 1) {
    if (t < s) sm[t] += sm[t + s];
    __syncthreads();
  }
  if (t == 0) bsums[blockIdx.x] = sm[0];
}

__global__ void k_scan2(int* __restrict__ bsums, int nb) {
  __shared__ int sm[128];
  int t = threadIdx.x;
  int v = (t < nb) ? bsums[t] : 0;
  sm[t] = v;
  __syncthreads();
  for (int off = 1; off < 128; off <<= 1) {
    int x = (t >= off) ? sm[t - off] : 0;
    __syncthreads();
    sm[t] += x;
    __syncthreads();
  }
  if (t < nb) bsums[t] = sm[t] - v;  // exclusive
}

// exclusive scan -> out (may alias in); optional sentinel out[n] = total.
__global__ __launch_bounds__(1024) void k_scan3s(const int* __restrict__ in,
                                                 const int* __restrict__ bsums,
                                                 int* __restrict__ out, int n,
                                                 int sentinel) {
  __shared__ int sm[1024];
  int t = threadIdx.x;
  long i = (long)blockIdx.x * 1024 + t;
  int v = (i < n) ? in[i] : 0;
  sm[t] = v;
  __syncthreads();
  for (int off = 1; off < 1024; off <<= 1) {
    int x = (t >= off) ? sm[t - off] : 0;
    __syncthreads();
    sm[t] += x;
    __syncthreads();
  }
  int excl = sm[t] - v + bsums[blockIdx.x];
  if (i < n) out[i] = excl;
  if (sentinel && i == n - 1) out[n] = excl + v;
}

__device__ __forceinline__ float bfu(unsigned short u) {
  return __uint_as_float((unsigned)u << 16);
}
__device__ __forceinline__ float bf_lo(unsigned u) {
  return __uint_as_float(u << 16);
}
__device__ __forceinline__ float bf_hi(unsigned u) {
  return __uint_as_float(u & 0xffff0000u);
}
__device__ __forceinline__ unsigned pack_bf2(float lo, float hi) {
  __hip_bfloat16 a = __float2bfloat16(lo), b = __float2bfloat16(hi);
  return (unsigned)*(unsigned short*)&a | ((unsigned)*(unsigned short*)&b << 16);
}

// C[n, M] = act(A[n, K] @ W[K, M] (+ bias)); W row-major [K][M], staged in LDS.
// K-loop pinned to no-unroll + manual next-k prefetch.
// ABF16: A rows are bf16. OBF16: write output as bf16 (RNE).
template <int K, int M, bool BIAS, int ACT, bool ABF16, bool OBF16>
__global__ __launch_bounds__(256) void k_gemm(const void* __restrict__ Av,
                                              const float* __restrict__ W,
                                              const float* __restrict__ bias,
                                              void* __restrict__ Cout, int nrows) {
  constexpr int CP = 4;
  constexpr int TPR = M / CP;        // threads per row
  constexpr int RG = 256 / TPR;      // row-groups per block
  constexpr int RP = 4;              // rows per thread
  constexpr int RT = RG * RP;        // rows per block
  __shared__ __align__(16) float sW[K * M];
  __shared__ __align__(16) float sB[BIAS ? M : 4];

  for (int i = threadIdx.x; i < K * M / 4; i += 256)
    ((float4*)sW)[i] = ((const float4*)W)[i];
  if (BIAS)
    for (int i = threadIdx.x; i < M; i += 256) sB[i] = bias[i];
  __syncthreads();

  const int cg = threadIdx.x % TPR;
  const int rg = threadIdx.x / TPR;
  const long row0 = (long)blockIdx.x * RT + rg;

  const float4* Apf[RP];
  const ushort4* Apb[RP];
  bool valid[RP];
#pragma unroll
  for (int r = 0; r < RP; ++r) {
    long row = row0 + (long)r * RG;
    valid[r] = (row < nrows);
    long rr = valid[r] ? row : 0;
    if (ABF16) Apb[r] = (const ushort4*)((const unsigned short*)Av + rr * K);
    else       Apf[r] = (const float4*)((const float*)Av + rr * K);
  }

  auto loadA = [&](int r, int k4) -> float4 {
    if (!valid[r]) return make_float4(0.f, 0.f, 0.f, 0.f);
    if (ABF16) {
      ushort4 q = Apb[r][k4];
      return make_float4(bfu(q.x), bfu(q.y), bfu(q.z), bfu(q.w));
    }
    return Apf[r][k4];
  };

  float acc[RP][CP] = {};
  float4 a[RP];
#pragma unroll
  for (int r = 0; r < RP; ++r) a[r] = loadA(r, 0);

#pragma unroll 1
  for (int k0 = 0; k0 < K - 4; k0 += 4) {
    float4 an[RP];
#pragma unroll
    for (int r = 0; r < RP; ++r) an[r] = loadA(r, k0 / 4 + 1);
#pragma unroll
    for (int j = 0; j < 4; ++j) {
      float4 w = ((const float4*)(sW + (k0 + j) * M))[cg];
#pragma unroll
      for (int r = 0; r < RP; ++r) {
        float av = (j == 0) ? a[r].x : (j == 1) ? a[r].y : (j == 2) ? a[r].z : a[r].w;
        acc[r][0] += av * w.x;
        acc[r][1] += av * w.y;
        acc[r][2] += av * w.z;
        acc[r][3] += av * w.w;
      }
    }
#pragma unroll
    for (int r = 0; r < RP; ++r) a[r] = an[r];
  }
  {  // last k-step
    const int k0 = K - 4;
#pragma unroll
    for (int j = 0; j < 4; ++j) {
      float4 w = ((const float4*)(sW + (k0 + j) * M))[cg];
#pragma unroll
      for (int r = 0; r < RP; ++r) {
        float av = (j == 0) ? a[r].x : (j == 1) ? a[r].y : (j == 2) ? a[r].z : a[r].w;
        acc[r][0] += av * w.x;
        acc[r][1] += av * w.y;
        acc[r][2] += av * w.z;
        acc[r][3] += av * w.w;
      }
    }
  }

#pragma unroll
  for (int r = 0; r < RP; ++r) {
    long row = row0 + (long)r * RG;
    if (row >= nrows) continue;
    float4 o = make_float4(acc[r][0], acc[r][1], acc[r][2], acc[r][3]);
    if (BIAS) {
      float4 bb = ((const float4*)sB)[cg];
      o.x += bb.x; o.y += bb.y; o.z += bb.z; o.w += bb.w;
    }
    if (ACT == 1) {
      o.x = fmaxf(o.x, 0.f); o.y = fmaxf(o.y, 0.f);
      o.z = fmaxf(o.z, 0.f); o.w = fmaxf(o.w, 0.f);
    }
    if (OBF16) {
      uint2 pk;
      pk.x = pack_bf2(o.x, o.y);
      pk.y = pack_bf2(o.z, o.w);
      ((uint2*)((__hip_bfloat16*)Cout + row * M))[cg] = pk;
    } else {
      ((float4*)((float*)Cout + row * M))[cg] = o;
    }
  }
}

// Fused agg64 + GEMM2: gather h1 row (fp32, registers) per node, stage in
// LDS, then hw2 = h1 @ W2 (bf16 out) in the same block. 16 lanes/node,
// 16 nodes/block, unroll 8 gather.
__global__ __launch_bounds__(256) void k_agg64g(const uint2* __restrict__ hw,
                                                const int* __restrict__ csr,
                                                const int* __restrict__ rs,
                                                const int* __restrict__ cnt,
                                                const float* __restrict__ dis,
                                                const float* __restrict__ b,
                                                const float* __restrict__ W2,
                                                unsigned* __restrict__ hw2,
                                                int n) {
  __shared__ __align__(16) float sW2[64 * 32];  // 8 KB
  __shared__ __align__(16) float sH[16][68];    // 4.25 KB, padded stride
  int t = threadIdx.x;
  for (int i = t; i < 64 * 32 / 4; i += 256)
    ((float4*)sW2)[i] = ((const float4*)W2)[i];

  unsigned nd = t >> 4;
  unsigned node = blockIdx.x * 16u + nd;
  unsigned f4 = t & 15;
  bool ok = (node < (unsigned)n);
  float o0 = 0.f, o1 = 0.f, o2 = 0.f, o3 = 0.f;
  if (ok) {
    float dsn = dis[node];
    uint2 su = hw[node * 16u + f4];
    float d2 = dsn * dsn;
    float a0 = bf_lo(su.x) * d2, a1 = bf_hi(su.x) * d2;
    float a2 = bf_lo(su.y) * d2, a3 = bf_hi(su.y) * d2;
    int start = rs[node], deg = cnt[node];
    int e = 0;
    for (; e + 7 < deg; e += 8) {
      unsigned s0 = (unsigned)csr[start + e];
      unsigned s1 = (unsigned)csr[start + e + 1];
      unsigned s2 = (unsigned)csr[start + e + 2];
      unsigned s3 = (unsigned)csr[start + e + 3];
      unsigned s4 = (unsigned)csr[start + e + 4];
      unsigned s5 = (unsigned)csr[start + e + 5];
      unsigned s6 = (unsigned)csr[start + e + 6];
      unsigned s7 = (unsigned)csr[start + e + 7];
      float w0 = dis[s0] * dsn, w1 = dis[s1] * dsn;
      float w2 = dis[s2] * dsn, w3 = dis[s3] * dsn;
      float w4 = dis[s4] * dsn, w5 = dis[s5] * dsn;
      float w6 = dis[s6] * dsn, w7 = dis[s7] * dsn;
      uint2 u0 = hw[s0 * 16u + f4];
      uint2 u1 = hw[s1 * 16u + f4];
      uint2 u2 = hw[s2 * 16u + f4];
      uint2 u3 = hw[s3 * 16u + f4];
      uint2 u4 = hw[s4 * 16u + f4];
      uint2 u5 = hw[s5 * 16u + f4];
      uint2 u6 = hw[s6 * 16u + f4];
      uint2 u7 = hw[s7 * 16u + f4];
      a0 += bf_lo(u0.x) * w0 + bf_lo(u1.x) * w1 + bf_lo(u2.x) * w2 + bf_lo(u3.x) * w3
          + bf_lo(u4.x) * w4 + bf_lo(u5.x) * w5 + bf_lo(u6.x) * w6 + bf_lo(u7.x) * w7;
      a1 += bf_hi(u0.x) * w0 + bf_hi(u1.x) * w1 + bf_hi(u2.x) * w2 + bf_hi(u3.x) * w3
          + bf_hi(u4.x) * w4 + bf_hi(u5.x) * w5 + bf_hi(u6.x) * w6 + bf_hi(u7.x) * w7;
      a2 += bf_lo(u0.y) * w0 + bf_lo(u1.y) * w1 + bf_lo(u2.y) * w2 + bf_lo(u3.y) * w3
          + bf_lo(u4.y) * w4 + bf_lo(u5.y) * w5 + bf_lo(u6.y) * w6 + bf_lo(u7.y) * w7;
      a3 += bf_hi(u0.y) * w0 + bf_hi(u1.y) * w1 + bf_hi(u2.y) * w2 + bf_hi(u3.y) * w3
          + bf_hi(u4.y) * w4 + bf_hi(u5.y) * w5 + bf_hi(u6.y) * w6 + bf_hi(u7.y) * w7;
    }
    for (; e < deg; ++e) {
      unsigned s0 = (unsigned)csr[start + e];
      float w0 = dis[s0] * dsn;
      uint2 u0 = hw[s0 * 16u + f4];
      a0 += bf_lo(u0.x) * w0;
      a1 += bf_hi(u0.x) * w0;
      a2 += bf_lo(u0.y) * w0;
      a3 += bf_hi(u0.y) * w0;
    }
    float4 bb = ((const float4*)b)[f4];
    o0 = fmaxf(a0 + bb.x, 0.f);  // relu(agg + b1) = h1, fp32
    o1 = fmaxf(a1 + bb.y, 0.f);
    o2 = fmaxf(a2 + bb.z, 0.f);
    o3 = fmaxf(a3 + bb.w, 0.f);
  }
  ((float4*)&sH[nd][4 * f4])[0] = make_float4(o0, o1, o2, o3);
  __syncthreads();
  if (ok) {
    float acc0 = 0.f, acc1 = 0.f;
#pragma unroll 8
    for (int k = 0; k < 64; ++k) {
      float hv = sH[nd][k];
      float2 w = *(const float2*)(sW2 + k * 32 + 2 * f4);
      acc0 += hv * w.x;
      acc1 += hv * w.y;
    }
    hw2[node * 16u + f4] = pack_bf2(acc0, acc1);
  }
}

// Fused agg32 + tail: 32 nodes/block, 256 threads. Gather keeps agg32p's
// exact geometry (8 lanes/node, unroll 8, register acc) and ~30KB LDS
// (5 blocks/CU, same occupancy class). h -> global (output) + LDS; then
// t = relu(h@rW1+rb1) (LDS), x_rec = t@rW2+rb2 (rW2 from global, L2-
// resident block-broadcast), s = relu(h@sW1+sb1) (LDS), score -> global.
__global__ __launch_bounds__(256) void k_aggtail(const uint2* __restrict__ hw,
                                                 const int* __restrict__ csr,
                                                 const int* __restrict__ rs,
                                                 const int* __restrict__ cnt,
                                                 const float* __restrict__ dis,
                                                 const float* __restrict__ b2,
                                                 const float* __restrict__ rW1,
                                                 const float* __restrict__ rb1,
                                                 const float* __restrict__ rW2,
                                                 const float* __restrict__ rb2,
                                                 const float* __restrict__ sW1,
                                                 const float* __restrict__ sb1,
                                                 const float* __restrict__ sW2,
                                                 const float* __restrict__ sb2,
                                                 float* __restrict__ h_out,
                                                 float* __restrict__ x_rec,
                                                 float* __restrict__ score, int n) {
  __shared__ __align__(16) float sRW1[32 * 64];    // 8 KB
  __shared__ __align__(16) float sSW1[32 * 32];    // 4 KB
  __shared__ __align__(16) float sRB1[64];
  __shared__ __align__(16) float sRB2[128];
  __shared__ __align__(16) float sSB1[32];
  __shared__ __align__(16) float sSW2[32];
  __shared__ float sH[32 * 33];                    // 4.2 KB
  __shared__ float sT[32 * 65];                    // 8.3 KB
  __shared__ float sS[32 * 33];                    // 4.2 KB
  int t = threadIdx.x;
  for (int i = t; i < 32 * 64 / 4; i += 256) ((float4*)sRW1)[i] = ((const float4*)rW1)[i];
  for (int i = t; i < 32 * 32 / 4; i += 256) ((float4*)sSW1)[i] = ((const float4*)sW1)[i];
  if (t < 64) sRB1[t] = rb1[t];
  else if (t < 192) sRB2[t - 64] = rb2[t - 64];
  else if (t < 224) sSB1[t - 192] = sb1[t - 192];
  else sSW2[t - 224] = sW2[t - 224];

  // ---- gather phase (agg32p geometry: 8 lanes/node, 32 nodes/block) ----
  unsigned ndl = t >> 3;                 // local node 0..31
  unsigned node = blockIdx.x * 32u + ndl;
  unsigned f4 = t & 7;
  bool ok = (node < (unsigned)n);
  float o0 = 0.f, o1 = 0.f, o2 = 0.f, o3 = 0.f;
  if (ok) {
    float dsn = dis[node];
    uint2 su = hw[node * 8u + f4];
    float d2 = dsn * dsn;
    float a0 = bf_lo(su.x) * d2, a1 = bf_hi(su.x) * d2;
    float a2 = bf_lo(su.y) * d2, a3 = bf_hi(su.y) * d2;
    int start = rs[node], deg = cnt[node];
    int e = 0;
    for (; e + 7 < deg; e += 8) {
      unsigned s0 = (unsigned)csr[start + e];
      unsigned s1 = (unsigned)csr[start + e + 1];
      unsigned s2 = (unsigned)csr[start + e + 2];
      unsigned s3 = (unsigned)csr[start + e + 3];
      unsigned s4 = (unsigned)csr[start + e + 4];
      unsigned s5 = (unsigned)csr[start + e + 5];
      unsigned s6 = (unsigned)csr[start + e + 6];
      unsigned s7 = (unsigned)csr[start + e + 7];
      float w0 = dis[s0] * dsn, w1 = dis[s1] * dsn;
      float w2 = dis[s2] * dsn, w3 = dis[s3] * dsn;
      float w4 = dis[s4] * dsn, w5 = dis[s5] * dsn;
      float w6 = dis[s6] * dsn, w7 = dis[s7] * dsn;
      uint2 u0 = hw[s0 * 8u + f4];
      uint2 u1 = hw[s1 * 8u + f4];
      uint2 u2 = hw[s2 * 8u + f4];
      uint2 u3 = hw[s3 * 8u + f4];
      uint2 u4 = hw[s4 * 8u + f4];
      uint2 u5 = hw[s5 * 8u + f4];
      uint2 u6 = hw[s6 * 8u + f4];
      uint2 u7 = hw[s7 * 8u + f4];
      a0 += bf_lo(u0.x) * w0 + bf_lo(u1.x) * w1 + bf_lo(u2.x) * w2 + bf_lo(u3.x) * w3
          + bf_lo(u4.x) * w4 + bf_lo(u5.x) * w5 + bf_lo(u6.x) * w6 + bf_lo(u7.x) * w7;
      a1 += bf_hi(u0.x) * w0 + bf_hi(u1.x) * w1 + bf_hi(u2.x) * w2 + bf_hi(u3.x) * w3
          + bf_hi(u4.x) * w4 + bf_hi(u5.x) * w5 + bf_hi(u6.x) * w6 + bf_hi(u7.x) * w7;
      a2 += bf_lo(u0.y) * w0 + bf_lo(u1.y) * w1 + bf_lo(u2.y) * w2 + bf_lo(u3.y) * w3
          + bf_lo(u4.y) * w4 + bf_lo(u5.y) * w5 + bf_lo(u6.y) * w6 + bf_lo(u7.y) * w7;
      a3 += bf_hi(u0.y) * w0 + bf_hi(u1.y) * w1 + bf_hi(u2.y) * w2 + bf_hi(u3.y) * w3
          + bf_hi(u4.y) * w4 + bf_hi(u5.y) * w5 + bf_hi(u6.y) * w6 + bf_hi(u7.y) * w7;
    }
    for (; e < deg; ++e) {
      unsigned s0 = (unsigned)csr[start + e];
      float w0 = dis[s0] * dsn;
      uint2 u0 = hw[s0 * 8u + f4];
      a0 += bf_lo(u0.x) * w0;
      a1 += bf_hi(u0.x) * w0;
      a2 += bf_lo(u0.y) * w0;
      a3 += bf_hi(u0.y) * w0;
    }
    float4 bb = ((const float4*)b2)[f4];
    o0 = a0 + bb.x; o1 = a1 + bb.y; o2 = a2 + bb.z; o3 = a3 + bb.w;
    ((float4*)(h_out + node * 32u))[f4] = make_float4(o0, o1, o2, o3);
  }
  sH[ndl * 33 + 4 * f4]     = o0;
  sH[ndl * 33 + 4 * f4 + 1] = o1;
  sH[ndl * 33 + 4 * f4 + 2] = o2;
  sH[ndl * 33 + 4 * f4 + 3] = o3;
  __syncthreads();

  long base = (long)blockIdx.x * 32;
  int nn = (int)min(32L, (long)n - base);
  if (nn < 0) nn = 0;

  {  // phase T: 32 rows x 64 cols; TPR=16, RG=16, RP=2
    int cg = t & 15, rg = t >> 4;
    float acc[2][4] = {};
    for (int k = 0; k < 32; ++k) {
      float4 w = ((const float4*)(sRW1 + k * 64))[cg];
      float a0 = sH[rg * 33 + k];
      float a1 = sH[(rg + 16) * 33 + k];
      acc[0][0] += a0 * w.x; acc[0][1] += a0 * w.y; acc[0][2] += a0 * w.z; acc[0][3] += a0 * w.w;
      acc[1][0] += a1 * w.x; acc[1][1] += a1 * w.y; acc[1][2] += a1 * w.z; acc[1][3] += a1 * w.w;
    }
    float4 bb = ((const float4*)sRB1)[cg];
#pragma unroll
    for (int m = 0; m < 2; ++m) {
      int row = rg + 16 * m;
      sT[row * 65 + 4 * cg]     = fmaxf(acc[m][0] + bb.x, 0.f);
      sT[row * 65 + 4 * cg + 1] = fmaxf(acc[m][1] + bb.y, 0.f);
      sT[row * 65 + 4 * cg + 2] = fmaxf(acc[m][2] + bb.z, 0.f);
      sT[row * 65 + 4 * cg + 3] = fmaxf(acc[m][3] + bb.w, 0.f);
    }
  }
  {  // phase S: 32 rows x 32 cols; TPR=8, RG=32, RP=1
    int cg = t & 7, rg = t >> 3;
    float acc[4] = {};
    for (int k = 0; k < 32; ++k) {
      float4 w = ((const float4*)(sSW1 + k * 32))[cg];
      float a0 = sH[rg * 33 + k];
      acc[0] += a0 * w.x; acc[1] += a0 * w.y; acc[2] += a0 * w.z; acc[3] += a0 * w.w;
    }
    float4 bb = ((const float4*)sSB1)[cg];
    sS[rg * 33 + 4 * cg]     = fmaxf(acc[0] + bb.x, 0.f);
    sS[rg * 33 + 4 * cg + 1] = fmaxf(acc[1] + bb.y, 0.f);
    sS[rg * 33 + 4 * cg + 2] = fmaxf(acc[2] + bb.z, 0.f);
    sS[rg * 33 + 4 * cg + 3] = fmaxf(acc[3] + bb.w, 0.f);
  }
  __syncthreads();

  {  // phase X: 32 rows x 128 cols from sT @ rW2 (global, L2-broadcast)
    int cg = t & 31, rg = t >> 5;   // 8 row-groups, RP=4
    float acc[4][4] = {};
    for (int k = 0; k < 64; ++k) {
      float4 w = ((const float4*)(rW2 + k * 128))[cg];
#pragma unroll
      for (int m = 0; m < 4; ++m) {
        float a = sT[(rg + 8 * m) * 65 + k];
        acc[m][0] += a * w.x; acc[m][1] += a * w.y;
        acc[m][2] += a * w.z; acc[m][3] += a * w.w;
      }
    }
    float4 bb = ((const float4*)sRB2)[cg];
#pragma unroll
    for (int m = 0; m < 4; ++m) {
      int row = rg + 8 * m;
      if (row < nn) {
        float4 o = make_float4(acc[m][0] + bb.x, acc[m][1] + bb.y,
                               acc[m][2] + bb.z, acc[m][3] + bb.w);
        ((float4*)(x_rec + (base + row) * 128))[cg] = o;
      }
    }
  }
  if (t < nn) {  // score: one thread per node
    float acc = 0.f;
    for (int j = 0; j < 32; ++j) acc += sS[t * 33 + j] * sSW2[j];
    score[base + t] = 1.0f / (1.0f + expf(-(acc + sb2[0])));
  }
}

extern "C" void kernel_launch(void* const* d_in, const int* in_sizes, int n_in,
                              void* d_out, int out_size, void* d_ws, size_t ws_size,
                              hipStream_t stream) {
  const float* x   = (const float*)d_in[0];
  const void*  ei  = d_in[1];
  const float* W1  = (const float*)d_in[2];
  const float* b1  = (const float*)d_in[3];
  const float* W2  = (const float*)d_in[4];
  const float* b2  = (const float*)d_in[5];
  const float* rW1 = (const float*)d_in[6];
  const float* rb1 = (const float*)d_in[7];
  const float* rW2 = (const float*)d_in[8];
  const float* rb2 = (const float*)d_in[9];
  const float* sW1 = (const float*)d_in[10];
  const float* sb1 = (const float*)d_in[11];
  const float* sW2 = (const float*)d_in[12];
  const float* sb2 = (const float*)d_in[13];

  const int N = in_sizes[0] / 128;
  const int E = in_sizes[1] / 2;
  const int ndet = E < 4096 ? E : 4096;

  // bucket geometry: SPB = 1<<shift nodes per bucket, B buckets (<=256)
  int shift = 9;
  while ((((long)N + (1L << shift) - 1) >> shift) > 256) ++shift;
  const int SB = 32 - shift;               // src bits in packed pair
  const int B = (int)(((long)N + (1L << shift) - 1) >> shift);
  const int C = 512;                       // edge chunks
  const int CS = (E + C - 1) / C;          // edges per chunk
  const int L = B * C;

  // workspace layout (256B aligned chunks)
  char* w = (char*)d_ws;
  auto alloc = [&](size_t bytes) {
    char* p = w;
    w += (bytes + 255) & ~(size_t)255;
    return p;
  };
  int*   cnt    = (int*)alloc((size_t)N * 4);
  int*   rs     = (int*)alloc((size_t)N * 4);
  float* dis    = (float*)alloc((size_t)N * 4);
  int*   bsumsL = (int*)alloc(1024);
  int*   bscan  = (int*)alloc(((size_t)L + 1) * 4);
  int*   csr    = (int*)alloc((size_t)E * 4);
  unsigned* pairs = (unsigned*)alloc((size_t)E * 4);
  uint2* hw1 = (uint2*)alloc((size_t)N * 64 * 2);       // bf16 [N][64]
  unsigned* hw2 = (unsigned*)alloc((size_t)N * 32 * 2); // bf16 [N][32]

  float* h_out = (float*)d_out;                 // [N,32]
  float* x_rec = h_out + (long)N * 32;          // [N,128]
  float* score = x_rec + (long)N * 128;         // [N,1]

  // ---- CSR build (atomic-free two-level counting sort; self-detecting) ----
  k_binhist<<<C, 256, 0, stream>>>(ei, E, CS, B, shift, ndet, bscan, C);
  int nbL = (L + 1023) / 1024;
  k_scan1<<<nbL, 1024, 0, stream>>>(bscan, bsumsL, L);
  k_scan2<<<1, 128, 0, stream>>>(bsumsL, nbL);
  k_scan3s<<<nbL, 1024, 0, stream>>>(bscan, bsumsL, bscan, L, 1);  // in-place + sentinel
  k_binscatter<<<C, 256, 0, stream>>>(ei, E, CS, B, shift, SB, ndet, bscan, C, pairs);
  k_bucketbuild<<<B, 256, 0, stream>>>(pairs, bscan, C, shift, SB, N, cnt, dis, rs, csr);

  // ---- layer 1 + GEMM2 fused: hw1 = bf16(x @ W1) ;
  //      h1 = relu(agg + b1) (fp32, LDS-only) ; hw2 = bf16(h1 @ W2) ----
  k_gemm<128, 64, false, 0, false, true><<<(N + 63) / 64, 256, 0, stream>>>(x, W1, nullptr, hw1, N);
  k_agg64g<<<(N + 15) / 16, 256, 0, stream>>>(hw1, csr, rs, cnt, dis, b1, W2, hw2, N);

  // ---- fused: h = agg(hw2)+b2 -> d_out ; recon MLP ; scorer MLP ----
  k_aggtail<<<(N + 31) / 32, 256, 0, stream>>>((const uint2*)hw2, csr, rs, cnt, dis, b2,
                                               rW1, rb1, rW2, rb2, sW1, sb1, sW2, sb2,
                                               h_out, x_rec, score, N);
}